// Round 7
// baseline (4083.034 us; speedup 1.0000x reference)
//
#include <hip/hip_runtime.h>
#include <cstdint>
#include <cstddef>

#define T_STEPS 32
#define BNROWS  2048     // B*N
#define C_DIM   512
#define H_DIM   1024
#define O_DIM   512
#define TBN_DIM 65536    // T_STEPS*BNROWS

typedef __attribute__((ext_vector_type(8))) short bf16x8;
typedef __attribute__((ext_vector_type(4))) float f32x4;

__device__ __forceinline__ float bf2f(unsigned short u){
    return __uint_as_float(((unsigned int)u) << 16);
}

// Exact 3-way truncation split: x == h + m + l exactly.
__device__ __forceinline__ void split3(float x, unsigned short& h,
                                       unsigned short& m, unsigned short& l){
    unsigned u = __float_as_uint(x);
    h = (unsigned short)(u >> 16);
    float r1 = x - __uint_as_float(u & 0xFFFF0000u);
    unsigned u1 = __float_as_uint(r1);
    m = (unsigned short)(u1 >> 16);
    float r2 = r1 - __uint_as_float(u1 & 0xFFFF0000u);
    l = (unsigned short)(__float_as_uint(r2) >> 16);
}

__global__ void split3_w(const float* __restrict__ src,
                         unsigned short* __restrict__ hi,
                         unsigned short* __restrict__ mi,
                         unsigned short* __restrict__ lo, int n4)
{
    int i = blockIdx.x * blockDim.x + threadIdx.x;
    int stride = gridDim.x * blockDim.x;
    for (; i < n4; i += stride) {
        float4 v = ((const float4*)src)[i];
        ushort4 h, m, l;
        split3(v.x, h.x, m.x, l.x); split3(v.y, h.y, m.y, l.y);
        split3(v.z, h.z, m.z, l.z); split3(v.w, h.w, m.w, l.w);
        ((ushort4*)hi)[i] = h;
        ((ushort4*)mi)[i] = m;
        ((ushort4*)lo)[i] = l;
    }
}

// 8-byte-granular LDS helpers for the MFMA kernel (LP=40 ushort rows = 80 B)
__device__ __forceinline__ void st8x2(unsigned short* p, int4 v){
    ((int2*)p)[0] = make_int2(v.x, v.y);
    ((int2*)p)[1] = make_int2(v.z, v.w);
}
__device__ __forceinline__ bf16x8 ld_frag(const unsigned short* p){
    union { bf16x8 v; ushort4 u[2]; } t;
    t.u[0] = *(const ushort4*)(p);
    t.u[1] = *(const ushort4*)(p + 4);
    return t.v;
}

// t=0 PLIF step (prev spikes all zero). Bit-exact to the GEMM-of-zeros path.
__global__ void step0_kernel(const float* __restrict__ curr0,
                             const float* __restrict__ brec,
                             const float* __restrict__ wlif,
                             float* __restrict__ vstate,
                             unsigned short* __restrict__ spk0)
{
    const float decay = 1.f / (1.f + expf(-wlif[0]));
    int i = blockIdx.x * blockDim.x + threadIdx.x;
    int stride = gridDim.x * blockDim.x;
    const int n4 = BNROWS * H_DIM / 4;
    for (; i < n4; i += stride) {
        float4 c = ((const float4*)curr0)[i];
        int col4 = (i * 4) & (H_DIM - 1);
        float4 b = *(const float4*)&brec[col4];
        float v0 = __fmul_rn(__fadd_rn(b.x, c.x), decay);
        float v1 = __fmul_rn(__fadd_rn(b.y, c.y), decay);
        float v2 = __fmul_rn(__fadd_rn(b.z, c.z), decay);
        float v3 = __fmul_rn(__fadd_rn(b.w, c.w), decay);
        bool s0 = (v0 - 1.0f) >= 0.0f, s1 = (v1 - 1.0f) >= 0.0f;
        bool s2 = (v2 - 1.0f) >= 0.0f, s3 = (v3 - 1.0f) >= 0.0f;
        float4 vo; vo.x = s0 ? 0.f : v0; vo.y = s1 ? 0.f : v1;
        vo.z = s2 ? 0.f : v2; vo.w = s3 ? 0.f : v3;
        ushort4 sp;
        sp.x = s0 ? 0x3F80 : 0; sp.y = s1 ? 0x3F80 : 0;
        sp.z = s2 ? 0x3F80 : 0; sp.w = s3 ? 0x3F80 : 0;
        ((float4*)vstate)[i] = vo;
        ((ushort4*)spk0)[i]  = sp;
    }
}

// ======== fp32 VALU GEMM, single-buffered (round-5 proven structure).
// Per-output arithmetic is bit-identical to the round-1/5 passing kernel:
// same LDS slot values, same ascending-k fmaf chain, same epilogue
// expressions. Only the thread->output-column mapping changed (TN=8 case:
// split chunks {tx*4..+3} and {64+tx*4..+3}) to turn the 4-way LDS bank
// conflict on B-reads into the free 2-way pattern.
// MODE 0: fc1  -> Cout = acc + bias
// MODE 1: rec  -> PLIF update epilogue (reads curr_t, v; writes v, spikes)
template<int MODE, int BM, int BN, int BK, int TM, int TN, bool ABF16>
__global__ __launch_bounds__(256)
void gemm_fused(const void* __restrict__ Ap,
                const float* __restrict__ Bp,
                int K, int ldc,
                const float* __restrict__ bias,
                const float* __restrict__ curr_t,
                float* __restrict__ vstate,
                unsigned short* __restrict__ spk_out,
                const float* __restrict__ wlif,
                float* __restrict__ Cout)
{
    constexpr int BMP = BM + 4;
    constexpr int BNP = BN + 4;
    __shared__ float smem[BK*BMP + BK*BNP];
    float* As = smem;
    float* Bs = smem + BK*BMP;

    const int tid = threadIdx.x;
    constexpr int TXN = BN / TN;
    const int tx = tid % TXN;
    const int ty = tid / TXN;
    const int bm0 = blockIdx.y * BM;
    const int bn0 = blockIdx.x * BN;

    constexpr int CPR = BK / 4;   // float4 (or ushort4) chunks per row

    float acc[TM][TN];
#pragma unroll
    for (int i = 0; i < TM; ++i)
#pragma unroll
        for (int j = 0; j < TN; ++j) acc[i][j] = 0.f;

    for (int kt = 0; kt < K; kt += BK) {
        // ---- stage A tile -> As[k][m] ----
        if constexpr (ABF16) {
            const unsigned short* A = (const unsigned short*)Ap;
            constexpr int PT = (BM*BK/4)/256;
#pragma unroll
            for (int it = 0; it < PT; ++it) {
                int e   = it*256 + tid;
                int row = e / CPR;
                int c4  = e % CPR;
                ushort4 uv = *(const ushort4*)(A + (size_t)(bm0+row)*K + kt + c4*4);
                As[(c4*4+0)*BMP + row] = bf2f(uv.x);
                As[(c4*4+1)*BMP + row] = bf2f(uv.y);
                As[(c4*4+2)*BMP + row] = bf2f(uv.z);
                As[(c4*4+3)*BMP + row] = bf2f(uv.w);
            }
        } else {
            const float* A = (const float*)Ap;
            constexpr int PT = (BM*BK/4)/256;
#pragma unroll
            for (int it = 0; it < PT; ++it) {
                int e   = it*256 + tid;
                int row = e / CPR;
                int c4  = e % CPR;
                float4 fv = *(const float4*)(A + (size_t)(bm0+row)*K + kt + c4*4);
                As[(c4*4+0)*BMP + row] = fv.x;
                As[(c4*4+1)*BMP + row] = fv.y;
                As[(c4*4+2)*BMP + row] = fv.z;
                As[(c4*4+3)*BMP + row] = fv.w;
            }
        }
        // ---- stage B tile -> Bs[k][n] ----
        {
            constexpr int PT = (BN*BK/4)/256;
#pragma unroll
            for (int it = 0; it < PT; ++it) {
                int e   = it*256 + tid;
                int row = e / CPR;
                int c4  = e % CPR;
                float4 fv = *(const float4*)(Bp + (size_t)(bn0+row)*K + kt + c4*4);
                Bs[(c4*4+0)*BNP + row] = fv.x;
                Bs[(c4*4+1)*BNP + row] = fv.y;
                Bs[(c4*4+2)*BNP + row] = fv.z;
                Bs[(c4*4+3)*BNP + row] = fv.w;
            }
        }
        __syncthreads();
#pragma unroll
        for (int k = 0; k < BK; ++k) {
            float a[TM], b[TN];
            if constexpr (TM == 8) {
                float4 t0 = *(const float4*)&As[k*BMP + ty*8];
                float4 t1 = *(const float4*)&As[k*BMP + ty*8 + 4];
                a[0]=t0.x; a[1]=t0.y; a[2]=t0.z; a[3]=t0.w;
                a[4]=t1.x; a[5]=t1.y; a[6]=t1.z; a[7]=t1.w;
            } else if constexpr (TM == 4) {
                float4 t0 = *(const float4*)&As[k*BMP + ty*4];
                a[0]=t0.x; a[1]=t0.y; a[2]=t0.z; a[3]=t0.w;
            } else {   // TM == 2
                float2 t0 = *(const float2*)&As[k*BMP + ty*2];
                a[0]=t0.x; a[1]=t0.y;
            }
            if constexpr (TN == 8) {
                // split-chunk mapping: banks 2-way (free) instead of 4-way
                float4 t0 = *(const float4*)&Bs[k*BNP + tx*4];
                float4 t1 = *(const float4*)&Bs[k*BNP + 64 + tx*4];
                b[0]=t0.x; b[1]=t0.y; b[2]=t0.z; b[3]=t0.w;
                b[4]=t1.x; b[5]=t1.y; b[6]=t1.z; b[7]=t1.w;
            } else {   // TN == 4
                float4 t0 = *(const float4*)&Bs[k*BNP + tx*4];
                b[0]=t0.x; b[1]=t0.y; b[2]=t0.z; b[3]=t0.w;
            }
#pragma unroll
            for (int i = 0; i < TM; ++i)
#pragma unroll
                for (int j = 0; j < TN; ++j)
                    acc[i][j] = fmaf(a[i], b[j], acc[i][j]);
        }
        __syncthreads();
    }

    if constexpr (MODE == 0) {
#pragma unroll
        for (int i = 0; i < TM; ++i) {
            int m = bm0 + ty*TM + i;
            if constexpr (TN == 8) {
                int n0 = bn0 + tx*4;
                int n1 = bn0 + 64 + tx*4;
                float4 bv0 = *(const float4*)&bias[n0];
                float4 bv1 = *(const float4*)&bias[n1];
                float4 o0, o1;
                o0.x = acc[i][0] + bv0.x; o0.y = acc[i][1] + bv0.y;
                o0.z = acc[i][2] + bv0.z; o0.w = acc[i][3] + bv0.w;
                o1.x = acc[i][4] + bv1.x; o1.y = acc[i][5] + bv1.y;
                o1.z = acc[i][6] + bv1.z; o1.w = acc[i][7] + bv1.w;
                *(float4*)&Cout[(size_t)m*ldc + n0] = o0;
                *(float4*)&Cout[(size_t)m*ldc + n1] = o1;
            } else {
                int n0 = bn0 + tx*4;
                float4 bv = *(const float4*)&bias[n0];
                float4 o;
                o.x = acc[i][0] + bv.x; o.y = acc[i][1] + bv.y;
                o.z = acc[i][2] + bv.z; o.w = acc[i][3] + bv.w;
                *(float4*)&Cout[(size_t)m*ldc + n0] = o;
            }
        }
    } else {   // MODE == 1 (TN == 4)
        float decay = 1.f / (1.f + expf(-wlif[0]));
#pragma unroll
        for (int i = 0; i < TM; ++i) {
            int m = bm0 + ty*TM + i;
            int n0 = bn0 + tx*4;
            size_t idx = (size_t)m*H_DIM + n0;
            float4 bv = *(const float4*)&bias[n0];
            float4 cv = *(const float4*)&curr_t[idx];
            float4 vv = *(const float4*)&vstate[idx];
            float vin[4] = {vv.x, vv.y, vv.z, vv.w};
            float bb[4]  = {bv.x, bv.y, bv.z, bv.w};
            float cc[4]  = {cv.x, cv.y, cv.z, cv.w};
            float vo[4];
            unsigned short so[4];
#pragma unroll
            for (int j = 0; j < 4; ++j) {
                float inp = acc[i][j] + bb[j] + cc[j];
                float v2  = vin[j] + (inp - vin[j]) * decay;
                bool s = (v2 - 1.0f) >= 0.0f;
                vo[j] = s ? 0.0f : v2;
                so[j] = s ? (unsigned short)0x3F80 : (unsigned short)0;
            }
            float4 vstore; vstore.x=vo[0]; vstore.y=vo[1]; vstore.z=vo[2]; vstore.w=vo[3];
            ushort4 sstore; sstore.x=so[0]; sstore.y=so[1]; sstore.z=so[2]; sstore.w=so[3];
            *(float4*)&vstate[idx]  = vstore;
            *(ushort4*)&spk_out[idx] = sstore;
        }
    }
}

// ======== MFMA GEMM for fc2 only (feeds BN; loose tolerance) ========
template<int BM, int BN, int WM, int WN, int MI, int NI>
__global__ __launch_bounds__(256)
void mfma_fc2(const unsigned short* __restrict__ Aptr,
              const unsigned short* __restrict__ Bhi,
              const unsigned short* __restrict__ Bmi,
              int K,
              const float* __restrict__ bias,
              float* __restrict__ Cout, int ldc,
              float* __restrict__ partials)
{
    constexpr int LP  = 40;
    constexpr int APL = BM * LP;
    constexpr int BPL = BN * LP;
    __shared__ alignas(16) unsigned short sA[APL];
    __shared__ alignas(16) unsigned short sB[2 * BPL];

    const int nwg = gridDim.x * gridDim.y;
    const int f   = blockIdx.y * gridDim.x + blockIdx.x;
    const int q   = nwg >> 3;
    const int lg  = (f & 7) * q + (f >> 3);
    const int bn0  = (lg % gridDim.x) * BN;
    const int mblk = lg / gridDim.x;
    const int bm0  = mblk * BM;

    const int tid  = threadIdx.x;
    const int lane = tid & 63;
    const int wid  = tid >> 6;
    const int wr   = wid / WN;
    const int wc   = wid % WN;
    const int lr   = lane & 15;
    const int lk   = lane >> 4;

    f32x4 accB[MI][NI], accS[MI][NI];
#pragma unroll
    for (int i = 0; i < MI; ++i)
#pragma unroll
        for (int j = 0; j < NI; ++j) {
            accB[i][j] = (f32x4){0.f, 0.f, 0.f, 0.f};
            accS[i][j] = (f32x4){0.f, 0.f, 0.f, 0.f};
        }

    for (int kt = 0; kt < K; kt += 32) {
#pragma unroll
        for (int p = 0; p < BM / 64; ++p) {
            int e = p * 256 + tid;
            int row = e >> 2, c8 = e & 3;
            int4 v = *(const int4*)(Aptr + (size_t)(bm0 + row) * K + kt + c8 * 8);
            st8x2(&sA[row * LP + c8 * 8], v);
        }
#pragma unroll
        for (int p = 0; p < BN / 64; ++p) {
            int e = p * 256 + tid;
            int row = e >> 2, c8 = e & 3;
            size_t g = (size_t)(bn0 + row) * K + kt + c8 * 8;
            st8x2(&sB[row * LP + c8 * 8],       *(const int4*)(Bhi + g));
            st8x2(&sB[BPL + row * LP + c8 * 8], *(const int4*)(Bmi + g));
        }
        __syncthreads();

        bf16x8 af[MI], b0[NI], b1[NI];
#pragma unroll
        for (int i = 0; i < MI; ++i) {
            int r = wr * MI * 16 + i * 16 + lr;
            af[i] = ld_frag(&sA[r * LP + lk * 8]);
        }
#pragma unroll
        for (int j = 0; j < NI; ++j) {
            int r = wc * NI * 16 + j * 16 + lr;
            b0[j] = ld_frag(&sB[r * LP + lk * 8]);
            b1[j] = ld_frag(&sB[BPL + r * LP + lk * 8]);
        }
#pragma unroll
        for (int i = 0; i < MI; ++i)
#pragma unroll
            for (int j = 0; j < NI; ++j) {
                accB[i][j] = __builtin_amdgcn_mfma_f32_16x16x32_bf16(af[i], b0[j], accB[i][j], 0, 0, 0);
                accS[i][j] = __builtin_amdgcn_mfma_f32_16x16x32_bf16(af[i], b1[j], accS[i][j], 0, 0, 0);
            }
        __syncthreads();
    }

    float csum[NI], csq[NI];
#pragma unroll
    for (int j = 0; j < NI; ++j) { csum[j] = 0.f; csq[j] = 0.f; }
#pragma unroll
    for (int i = 0; i < MI; ++i)
#pragma unroll
        for (int j = 0; j < NI; ++j) {
            int col = bn0 + wc * NI * 16 + j * 16 + lr;
            float bv = bias[col];
#pragma unroll
            for (int r = 0; r < 4; ++r) {
                int row = bm0 + wr * MI * 16 + i * 16 + lk * 4 + r;
                float o = (accB[i][j][r] + accS[i][j][r]) + bv;
                Cout[(size_t)row * ldc + col] = o;
                csum[j] += o;
                csq[j]  += o * o;
            }
        }
    __syncthreads();
    float* redS = (float*)sA;
    float* redQ = (float*)sB;
    const int slot = wr * 4 + lk;
#pragma unroll
    for (int j = 0; j < NI; ++j) {
        int c = wc * NI * 16 + j * 16 + lr;
        redS[slot * BN + c] = csum[j];
        redQ[slot * BN + c] = csq[j];
    }
    __syncthreads();
    if (tid < BN) {
        float s = 0.f, qq = 0.f;
        for (int sl = 0; sl < WM * 4; ++sl) { s += redS[sl * BN + tid]; qq += redQ[sl * BN + tid]; }
        partials[((size_t)mblk * 2 + 0) * O_DIM + bn0 + tid] = s;
        partials[((size_t)mblk * 2 + 1) * O_DIM + bn0 + tid] = qq;
    }
}

__global__ void bn_finalize(const float* __restrict__ partials,
                            const float* __restrict__ gamma,
                            const float* __restrict__ beta,
                            float* __restrict__ scsh, int nmblk)
{
    int o = threadIdx.x;   // 512 threads
    float s = 0.f, q = 0.f;
    for (int mb = 0; mb < nmblk; ++mb) {
        s += partials[((size_t)mb*2 + 0)*O_DIM + o];
        q += partials[((size_t)mb*2 + 1)*O_DIM + o];
    }
    const float invn = 1.f / (float)TBN_DIM;
    float mean = s * invn;
    float var  = q * invn - mean*mean;
    float sc   = gamma[o] * rsqrtf(var + 1e-5f);
    scsh[o]        = sc;
    scsh[O_DIM+o]  = beta[o] - mean*sc;
}

__global__ void bn_apply(float* __restrict__ out, const float* __restrict__ scsh)
{
    const size_t total4 = (size_t)TBN_DIM * O_DIM / 4;
    const float4* sc4 = (const float4*)scsh;
    const float4* sh4 = (const float4*)(scsh + O_DIM);
    size_t stride = (size_t)gridDim.x * blockDim.x;
    for (size_t idx = (size_t)blockIdx.x*blockDim.x + threadIdx.x; idx < total4; idx += stride) {
        float4 v = ((float4*)out)[idx];
        int c4 = (int)(idx & (O_DIM/4 - 1));
        float4 sc = sc4[c4], sh = sh4[c4];
        v.x = v.x*sc.x + sh.x;
        v.y = v.y*sc.y + sh.y;
        v.z = v.z*sc.z + sh.z;
        v.w = v.w*sc.w + sh.w;
        ((float4*)out)[idx] = v;
    }
}

extern "C" void kernel_launch(void* const* d_in, const int* in_sizes, int n_in,
                              void* d_out, int out_size, void* d_ws, size_t ws_size,
                              hipStream_t stream) {
    const float* x     = (const float*)d_in[0];
    const float* W1    = (const float*)d_in[1];
    const float* b1    = (const float*)d_in[2];
    const float* Wrec  = (const float*)d_in[3];
    const float* brec  = (const float*)d_in[4];
    const float* wlif  = (const float*)d_in[5];
    const float* W2    = (const float*)d_in[6];
    const float* b2    = (const float*)d_in[7];
    const float* gamma = (const float*)d_in[8];
    const float* beta  = (const float*)d_in[9];
    float* out = (float*)d_out;

    // ws layout (~414.2 MB)
    char* w = (char*)d_ws;
    float*          curr   = (float*)w;                            // 256 MB
    unsigned short* spk    = (unsigned short*)(w + 268435456);     // 128 MB, slots 0..31
    float*          vstate = (float*)(w + 402653184);              // 8 MB
    unsigned short* w2p    = (unsigned short*)(w + 411041792);     // W2 3 planes, 3 MB
    float* partials = curr;                 // overlay: curr dead after scan
    float* scsh     = curr + 512 * 2 * O_DIM;

    const int W2N = O_DIM * H_DIM;          // 524288

    // fc1: curr = x @ W1^T + b1   (single-buffer fp32 engine + conflict remap)
    gemm_fused<0,128,128,16,8,8,false>
        <<<dim3(H_DIM/128, TBN_DIM/128), 256, 0, stream>>>(
            x, W1, C_DIM, H_DIM, b1,
            nullptr, nullptr, nullptr, nullptr, curr);

    // t=0 (bit-exact elementwise replacement of GEMM-of-zeros; inits vstate)
    step0_kernel<<<dim3(512), 256, 0, stream>>>(curr, brec, wlif, vstate, spk);

    // recurrent scan t=1..31 (32x64 tile -> 1024 blocks = 4/CU)
    for (int t = 1; t < T_STEPS; ++t) {
        gemm_fused<1,32,64,32,2,4,true>
            <<<dim3(H_DIM/64, BNROWS/32), 256, 0, stream>>>(
                spk + (size_t)(t-1) * BNROWS * H_DIM, Wrec, H_DIM, H_DIM, brec,
                curr + (size_t)t * BNROWS * H_DIM, vstate,
                spk + (size_t)t * BNROWS * H_DIM, wlif, nullptr);
    }

    // fc2 (BN-only consumer): 2-plane bf16 MFMA + fused BN partials
    split3_w<<<dim3(256), 256, 0, stream>>>(W2, w2p, w2p + W2N, w2p + 2 * W2N, W2N / 4);
    mfma_fc2<128, 128, 2, 2, 4, 4>
        <<<dim3(O_DIM/128, TBN_DIM/128), 256, 0, stream>>>(
            spk, w2p, w2p + W2N, H_DIM, b2, out, O_DIM, partials);

    bn_finalize<<<1, O_DIM, 0, stream>>>(partials, gamma, beta, scsh, TBN_DIM/128);
    bn_apply<<<2048, 256, 0, stream>>>(out, scsh);
}

// Round 8
// 3747.211 us; speedup vs baseline: 1.0896x; 1.0896x over previous
//
#include <hip/hip_runtime.h>
#include <cstdint>
#include <cstddef>

#define T_STEPS 32
#define BNROWS  2048     // B*N
#define C_DIM   512
#define H_DIM   1024
#define O_DIM   512
#define TBN_DIM 65536    // T_STEPS*BNROWS

typedef __attribute__((ext_vector_type(8))) short bf16x8;
typedef __attribute__((ext_vector_type(4))) float f32x4;

__device__ __forceinline__ float bf2f(unsigned short u){
    return __uint_as_float(((unsigned int)u) << 16);
}

// Exact 3-way truncation split: x == h + m + l exactly.
__device__ __forceinline__ void split3(float x, unsigned short& h,
                                       unsigned short& m, unsigned short& l){
    unsigned u = __float_as_uint(x);
    h = (unsigned short)(u >> 16);
    float r1 = x - __uint_as_float(u & 0xFFFF0000u);
    unsigned u1 = __float_as_uint(r1);
    m = (unsigned short)(u1 >> 16);
    float r2 = r1 - __uint_as_float(u1 & 0xFFFF0000u);
    l = (unsigned short)(__float_as_uint(r2) >> 16);
}

__global__ void split3_w(const float* __restrict__ src,
                         unsigned short* __restrict__ hi,
                         unsigned short* __restrict__ mi,
                         unsigned short* __restrict__ lo, int n4)
{
    int i = blockIdx.x * blockDim.x + threadIdx.x;
    int stride = gridDim.x * blockDim.x;
    for (; i < n4; i += stride) {
        float4 v = ((const float4*)src)[i];
        ushort4 h, m, l;
        split3(v.x, h.x, m.x, l.x); split3(v.y, h.y, m.y, l.y);
        split3(v.z, h.z, m.z, l.z); split3(v.w, h.w, m.w, l.w);
        ((ushort4*)hi)[i] = h;
        ((ushort4*)mi)[i] = m;
        ((ushort4*)lo)[i] = l;
    }
}

// 8-byte-granular LDS helpers for the MFMA kernel (LP=40 ushort rows = 80 B)
__device__ __forceinline__ void st8x2(unsigned short* p, int4 v){
    ((int2*)p)[0] = make_int2(v.x, v.y);
    ((int2*)p)[1] = make_int2(v.z, v.w);
}
__device__ __forceinline__ bf16x8 ld_frag(const unsigned short* p){
    union { bf16x8 v; ushort4 u[2]; } t;
    t.u[0] = *(const ushort4*)(p);
    t.u[1] = *(const ushort4*)(p + 4);
    return t.v;
}

// t=0 PLIF step (prev spikes all zero). Bit-exact to the GEMM-of-zeros path.
__global__ void step0_kernel(const float* __restrict__ curr0,
                             const float* __restrict__ brec,
                             const float* __restrict__ wlif,
                             float* __restrict__ vstate,
                             unsigned short* __restrict__ spk0)
{
    const float decay = 1.f / (1.f + expf(-wlif[0]));
    int i = blockIdx.x * blockDim.x + threadIdx.x;
    int stride = gridDim.x * blockDim.x;
    const int n4 = BNROWS * H_DIM / 4;
    for (; i < n4; i += stride) {
        float4 c = ((const float4*)curr0)[i];
        int col4 = (i * 4) & (H_DIM - 1);
        float4 b = *(const float4*)&brec[col4];
        float v0 = __fmul_rn(__fadd_rn(b.x, c.x), decay);
        float v1 = __fmul_rn(__fadd_rn(b.y, c.y), decay);
        float v2 = __fmul_rn(__fadd_rn(b.z, c.z), decay);
        float v3 = __fmul_rn(__fadd_rn(b.w, c.w), decay);
        bool s0 = (v0 - 1.0f) >= 0.0f, s1 = (v1 - 1.0f) >= 0.0f;
        bool s2 = (v2 - 1.0f) >= 0.0f, s3 = (v3 - 1.0f) >= 0.0f;
        float4 vo; vo.x = s0 ? 0.f : v0; vo.y = s1 ? 0.f : v1;
        vo.z = s2 ? 0.f : v2; vo.w = s3 ? 0.f : v3;
        ushort4 sp;
        sp.x = s0 ? 0x3F80 : 0; sp.y = s1 ? 0x3F80 : 0;
        sp.z = s2 ? 0x3F80 : 0; sp.w = s3 ? 0x3F80 : 0;
        ((float4*)vstate)[i] = vo;
        ((ushort4*)spk0)[i]  = sp;
    }
}

// ======== fc1: fp32 VALU GEMM, single-buffered (round-7 proven). ========
// Per-output arithmetic bit-identical to round-1/5/7 passing kernels.
template<int BM, int BN, int BK, int TM, int TN>
__global__ __launch_bounds__(256)
void gemm_fc1(const float* __restrict__ Ap,
              const float* __restrict__ Bp,
              int K, int ldc,
              const float* __restrict__ bias,
              float* __restrict__ Cout)
{
    constexpr int BMP = BM + 4;
    constexpr int BNP = BN + 4;
    __shared__ float smem[BK*BMP + BK*BNP];
    float* As = smem;
    float* Bs = smem + BK*BMP;

    const int tid = threadIdx.x;
    constexpr int TXN = BN / TN;
    const int tx = tid % TXN;
    const int ty = tid / TXN;
    const int bm0 = blockIdx.y * BM;
    const int bn0 = blockIdx.x * BN;

    constexpr int CPR = BK / 4;

    float acc[TM][TN];
#pragma unroll
    for (int i = 0; i < TM; ++i)
#pragma unroll
        for (int j = 0; j < TN; ++j) acc[i][j] = 0.f;

    for (int kt = 0; kt < K; kt += BK) {
        {
            constexpr int PT = (BM*BK/4)/256;
#pragma unroll
            for (int it = 0; it < PT; ++it) {
                int e   = it*256 + tid;
                int row = e / CPR;
                int c4  = e % CPR;
                float4 fv = *(const float4*)(Ap + (size_t)(bm0+row)*K + kt + c4*4);
                As[(c4*4+0)*BMP + row] = fv.x;
                As[(c4*4+1)*BMP + row] = fv.y;
                As[(c4*4+2)*BMP + row] = fv.z;
                As[(c4*4+3)*BMP + row] = fv.w;
            }
        }
        {
            constexpr int PT = (BN*BK/4)/256;
#pragma unroll
            for (int it = 0; it < PT; ++it) {
                int e   = it*256 + tid;
                int row = e / CPR;
                int c4  = e % CPR;
                float4 fv = *(const float4*)(Bp + (size_t)(bn0+row)*K + kt + c4*4);
                Bs[(c4*4+0)*BNP + row] = fv.x;
                Bs[(c4*4+1)*BNP + row] = fv.y;
                Bs[(c4*4+2)*BNP + row] = fv.z;
                Bs[(c4*4+3)*BNP + row] = fv.w;
            }
        }
        __syncthreads();
#pragma unroll
        for (int k = 0; k < BK; ++k) {
            float a[TM], b[TN];
            float4 t0 = *(const float4*)&As[k*BMP + ty*8];
            float4 t1 = *(const float4*)&As[k*BMP + ty*8 + 4];
            a[0]=t0.x; a[1]=t0.y; a[2]=t0.z; a[3]=t0.w;
            a[4]=t1.x; a[5]=t1.y; a[6]=t1.z; a[7]=t1.w;
            // split-chunk mapping: banks 2-way (free) instead of 4-way
            float4 u0 = *(const float4*)&Bs[k*BNP + tx*4];
            float4 u1 = *(const float4*)&Bs[k*BNP + 64 + tx*4];
            b[0]=u0.x; b[1]=u0.y; b[2]=u0.z; b[3]=u0.w;
            b[4]=u1.x; b[5]=u1.y; b[6]=u1.z; b[7]=u1.w;
#pragma unroll
            for (int i = 0; i < TM; ++i)
#pragma unroll
                for (int j = 0; j < TN; ++j)
                    acc[i][j] = fmaf(a[i], b[j], acc[i][j]);
        }
        __syncthreads();
    }

#pragma unroll
    for (int i = 0; i < TM; ++i) {
        int m = bm0 + ty*TM + i;
        int n0 = bn0 + tx*4;
        int n1 = bn0 + 64 + tx*4;
        float4 bv0 = *(const float4*)&bias[n0];
        float4 bv1 = *(const float4*)&bias[n1];
        float4 o0, o1;
        o0.x = acc[i][0] + bv0.x; o0.y = acc[i][1] + bv0.y;
        o0.z = acc[i][2] + bv0.z; o0.w = acc[i][3] + bv0.w;
        o1.x = acc[i][4] + bv1.x; o1.y = acc[i][5] + bv1.y;
        o1.z = acc[i][6] + bv1.z; o1.w = acc[i][7] + bv1.w;
        *(float4*)&Cout[(size_t)m*ldc + n0] = o0;
        *(float4*)&Cout[(size_t)m*ldc + n1] = o1;
    }
}

// ======== rec step: SPARSE ordered gather-sum + PLIF epilogue. ========
// out[m][n] = sum_{k ascending, spk[m][k]=1} Wrec[n][k]  — bit-identical to
// the dense ascending-k fmaf chain: fmaf(0,w,acc)==acc (acc can never be -0:
// starts +0, +0+(+/-0)=+0, x+(-x)=+0 in RNE), fmaf(1,w,acc)==acc+w (single
// rounding). Wave-uniform ballot mask -> scalar ctz loop, no divergence.
__global__ __launch_bounds__(256)
void rec_sparse(const unsigned short* __restrict__ spk_prev,
                const float* __restrict__ Wrec,     // [H][H] row-major
                const float* __restrict__ brec,
                const float* __restrict__ curr_t,
                const float* __restrict__ wlif,
                float* __restrict__ vstate,
                unsigned short* __restrict__ spk_out)
{
    constexpr int BM = 32, BN = 64, BK = 64, BNP = BN + 4;
    __shared__ float Bs[BK * BNP];   // 17.4 KB

    const int tid  = threadIdx.x;
    const int lane = tid & 63;
    const int wid  = tid >> 6;          // 4 waves
    const int bn0  = blockIdx.x * BN;   // 16 n-blocks
    const int bm0  = blockIdx.y * BM;   // 64 m-blocks
    const int r0   = wid * 8;           // 8 rows per wave

    float acc[8];
#pragma unroll
    for (int i = 0; i < 8; ++i) acc[i] = 0.f;

    for (int kt = 0; kt < H_DIM; kt += BK) {
        // stage Bs[k][n] = Wrec[bn0+n][kt+k]  (coalesced along k)
#pragma unroll
        for (int it = 0; it < (BN*BK/4)/256; ++it) {   // 4 iters
            int e   = it*256 + tid;
            int row = e >> 4;      // n 0..63
            int c4  = e & 15;      // 16 float4 chunks per row
            float4 fv = *(const float4*)(Wrec + (size_t)(bn0+row)*H_DIM + kt + c4*4);
            Bs[(c4*4+0)*BNP + row] = fv.x;
            Bs[(c4*4+1)*BNP + row] = fv.y;
            Bs[(c4*4+2)*BNP + row] = fv.z;
            Bs[(c4*4+3)*BNP + row] = fv.w;
        }
        __syncthreads();
#pragma unroll
        for (int i = 0; i < 8; ++i) {
            unsigned short sv =
                spk_prev[(size_t)(bm0 + r0 + i) * H_DIM + kt + lane];
            unsigned long long m = __ballot(sv != 0);
            while (m) {
                int k = __builtin_ctzll(m);
                m &= (m - 1);
                acc[i] += Bs[k * BNP + lane];
            }
        }
        __syncthreads();
    }

    const float decay = 1.f / (1.f + expf(-wlif[0]));
    const int n = bn0 + lane;
    const float bv = brec[n];
#pragma unroll
    for (int i = 0; i < 8; ++i) {
        int mrow = bm0 + r0 + i;
        size_t idx = (size_t)mrow * H_DIM + n;
        float inp = acc[i] + bv + curr_t[idx];
        float vv  = vstate[idx];
        vv = vv + (inp - vv) * decay;
        bool s = (vv - 1.0f) >= 0.0f;
        vstate[idx]  = s ? 0.0f : vv;
        spk_out[idx] = s ? (unsigned short)0x3F80 : (unsigned short)0;
    }
}

// ======== MFMA GEMM for fc2 only (feeds BN; loose tolerance) ========
template<int BM, int BN, int WM, int WN, int MI, int NI>
__global__ __launch_bounds__(256)
void mfma_fc2(const unsigned short* __restrict__ Aptr,
              const unsigned short* __restrict__ Bhi,
              const unsigned short* __restrict__ Bmi,
              int K,
              const float* __restrict__ bias,
              float* __restrict__ Cout, int ldc,
              float* __restrict__ partials)
{
    constexpr int LP  = 40;
    constexpr int APL = BM * LP;
    constexpr int BPL = BN * LP;
    __shared__ alignas(16) unsigned short sA[APL];
    __shared__ alignas(16) unsigned short sB[2 * BPL];

    const int nwg = gridDim.x * gridDim.y;
    const int f   = blockIdx.y * gridDim.x + blockIdx.x;
    const int q   = nwg >> 3;
    const int lg  = (f & 7) * q + (f >> 3);
    const int bn0  = (lg % gridDim.x) * BN;
    const int mblk = lg / gridDim.x;
    const int bm0  = mblk * BM;

    const int tid  = threadIdx.x;
    const int lane = tid & 63;
    const int wid  = tid >> 6;
    const int wr   = wid / WN;
    const int wc   = wid % WN;
    const int lr   = lane & 15;
    const int lk   = lane >> 4;

    f32x4 accB[MI][NI], accS[MI][NI];
#pragma unroll
    for (int i = 0; i < MI; ++i)
#pragma unroll
        for (int j = 0; j < NI; ++j) {
            accB[i][j] = (f32x4){0.f, 0.f, 0.f, 0.f};
            accS[i][j] = (f32x4){0.f, 0.f, 0.f, 0.f};
        }

    for (int kt = 0; kt < K; kt += 32) {
#pragma unroll
        for (int p = 0; p < BM / 64; ++p) {
            int e = p * 256 + tid;
            int row = e >> 2, c8 = e & 3;
            int4 v = *(const int4*)(Aptr + (size_t)(bm0 + row) * K + kt + c8 * 8);
            st8x2(&sA[row * LP + c8 * 8], v);
        }
#pragma unroll
        for (int p = 0; p < BN / 64; ++p) {
            int e = p * 256 + tid;
            int row = e >> 2, c8 = e & 3;
            size_t g = (size_t)(bn0 + row) * K + kt + c8 * 8;
            st8x2(&sB[row * LP + c8 * 8],       *(const int4*)(Bhi + g));
            st8x2(&sB[BPL + row * LP + c8 * 8], *(const int4*)(Bmi + g));
        }
        __syncthreads();

        bf16x8 af[MI], b0[NI], b1[NI];
#pragma unroll
        for (int i = 0; i < MI; ++i) {
            int r = wr * MI * 16 + i * 16 + lr;
            af[i] = ld_frag(&sA[r * LP + lk * 8]);
        }
#pragma unroll
        for (int j = 0; j < NI; ++j) {
            int r = wc * NI * 16 + j * 16 + lr;
            b0[j] = ld_frag(&sB[r * LP + lk * 8]);
            b1[j] = ld_frag(&sB[BPL + r * LP + lk * 8]);
        }
#pragma unroll
        for (int i = 0; i < MI; ++i)
#pragma unroll
            for (int j = 0; j < NI; ++j) {
                accB[i][j] = __builtin_amdgcn_mfma_f32_16x16x32_bf16(af[i], b0[j], accB[i][j], 0, 0, 0);
                accS[i][j] = __builtin_amdgcn_mfma_f32_16x16x32_bf16(af[i], b1[j], accS[i][j], 0, 0, 0);
            }
        __syncthreads();
    }

    float csum[NI], csq[NI];
#pragma unroll
    for (int j = 0; j < NI; ++j) { csum[j] = 0.f; csq[j] = 0.f; }
#pragma unroll
    for (int i = 0; i < MI; ++i)
#pragma unroll
        for (int j = 0; j < NI; ++j) {
            int col = bn0 + wc * NI * 16 + j * 16 + lr;
            float bv = bias[col];
#pragma unroll
            for (int r = 0; r < 4; ++r) {
                int row = bm0 + wr * MI * 16 + i * 16 + lk * 4 + r;
                float o = (accB[i][j][r] + accS[i][j][r]) + bv;
                Cout[(size_t)row * ldc + col] = o;
                csum[j] += o;
                csq[j]  += o * o;
            }
        }
    __syncthreads();
    float* redS = (float*)sA;
    float* redQ = (float*)sB;
    const int slot = wr * 4 + lk;
#pragma unroll
    for (int j = 0; j < NI; ++j) {
        int c = wc * NI * 16 + j * 16 + lr;
        redS[slot * BN + c] = csum[j];
        redQ[slot * BN + c] = csq[j];
    }
    __syncthreads();
    if (tid < BN) {
        float s = 0.f, qq = 0.f;
        for (int sl = 0; sl < WM * 4; ++sl) { s += redS[sl * BN + tid]; qq += redQ[sl * BN + tid]; }
        partials[((size_t)mblk * 2 + 0) * O_DIM + bn0 + tid] = s;
        partials[((size_t)mblk * 2 + 1) * O_DIM + bn0 + tid] = qq;
    }
}

__global__ void bn_finalize(const float* __restrict__ partials,
                            const float* __restrict__ gamma,
                            const float* __restrict__ beta,
                            float* __restrict__ scsh, int nmblk)
{
    int o = threadIdx.x;   // 512 threads
    float s = 0.f, q = 0.f;
    for (int mb = 0; mb < nmblk; ++mb) {
        s += partials[((size_t)mb*2 + 0)*O_DIM + o];
        q += partials[((size_t)mb*2 + 1)*O_DIM + o];
    }
    const float invn = 1.f / (float)TBN_DIM;
    float mean = s * invn;
    float var  = q * invn - mean*mean;
    float sc   = gamma[o] * rsqrtf(var + 1e-5f);
    scsh[o]        = sc;
    scsh[O_DIM+o]  = beta[o] - mean*sc;
}

__global__ void bn_apply(float* __restrict__ out, const float* __restrict__ scsh)
{
    const size_t total4 = (size_t)TBN_DIM * O_DIM / 4;
    const float4* sc4 = (const float4*)scsh;
    const float4* sh4 = (const float4*)(scsh + O_DIM);
    size_t stride = (size_t)gridDim.x * blockDim.x;
    for (size_t idx = (size_t)blockIdx.x*blockDim.x + threadIdx.x; idx < total4; idx += stride) {
        float4 v = ((float4*)out)[idx];
        int c4 = (int)(idx & (O_DIM/4 - 1));
        float4 sc = sc4[c4], sh = sh4[c4];
        v.x = v.x*sc.x + sh.x;
        v.y = v.y*sc.y + sh.y;
        v.z = v.z*sc.z + sh.z;
        v.w = v.w*sc.w + sh.w;
        ((float4*)out)[idx] = v;
    }
}

extern "C" void kernel_launch(void* const* d_in, const int* in_sizes, int n_in,
                              void* d_out, int out_size, void* d_ws, size_t ws_size,
                              hipStream_t stream) {
    const float* x     = (const float*)d_in[0];
    const float* W1    = (const float*)d_in[1];
    const float* b1    = (const float*)d_in[2];
    const float* Wrec  = (const float*)d_in[3];
    const float* brec  = (const float*)d_in[4];
    const float* wlif  = (const float*)d_in[5];
    const float* W2    = (const float*)d_in[6];
    const float* b2    = (const float*)d_in[7];
    const float* gamma = (const float*)d_in[8];
    const float* beta  = (const float*)d_in[9];
    float* out = (float*)d_out;

    // ws layout (~414.2 MB)
    char* w = (char*)d_ws;
    float*          curr   = (float*)w;                            // 256 MB
    unsigned short* spk    = (unsigned short*)(w + 268435456);     // 128 MB, slots 0..31
    float*          vstate = (float*)(w + 402653184);              // 8 MB
    unsigned short* w2p    = (unsigned short*)(w + 411041792);     // W2 3 planes, 3 MB
    float* partials = curr;                 // overlay: curr dead after scan
    float* scsh     = curr + 512 * 2 * O_DIM;

    const int W2N = O_DIM * H_DIM;          // 524288

    // fc1: curr = x @ W1^T + b1   (single-buffer fp32 engine + conflict remap)
    gemm_fc1<128,128,16,8,8>
        <<<dim3(H_DIM/128, TBN_DIM/128), 256, 0, stream>>>(
            x, W1, C_DIM, H_DIM, b1, curr);

    // t=0 (bit-exact elementwise replacement of GEMM-of-zeros; inits vstate)
    step0_kernel<<<dim3(512), 256, 0, stream>>>(curr, brec, wlif, vstate, spk);

    // recurrent scan t=1..31: sparse ordered gather-sum (bit-exact chain)
    for (int t = 1; t < T_STEPS; ++t) {
        rec_sparse<<<dim3(H_DIM/64, BNROWS/32), 256, 0, stream>>>(
            spk + (size_t)(t-1) * BNROWS * H_DIM, Wrec, brec,
            curr + (size_t)t * BNROWS * H_DIM, wlif, vstate,
            spk + (size_t)t * BNROWS * H_DIM);
    }

    // fc2 (BN-only consumer): 2-plane bf16 MFMA + fused BN partials
    split3_w<<<dim3(256), 256, 0, stream>>>(W2, w2p, w2p + W2N, w2p + 2 * W2N, W2N / 4);
    mfma_fc2<128, 128, 2, 2, 4, 4>
        <<<dim3(O_DIM/128, TBN_DIM/128), 256, 0, stream>>>(
            spk, w2p, w2p + W2N, H_DIM, b2, out, O_DIM, partials);

    bn_finalize<<<1, O_DIM, 0, stream>>>(partials, gamma, beta, scsh, TBN_DIM/128);
    bn_apply<<<2048, 256, 0, stream>>>(out, scsh);
}

// Round 9
// 3309.021 us; speedup vs baseline: 1.2339x; 1.1324x over previous
//
#include <hip/hip_runtime.h>
#include <cstdint>
#include <cstddef>

#define T_STEPS 32
#define BNROWS  2048     // B*N
#define C_DIM   512
#define H_DIM   1024
#define O_DIM   512
#define TBN_DIM 65536    // T_STEPS*BNROWS

typedef __attribute__((ext_vector_type(8))) short bf16x8;
typedef __attribute__((ext_vector_type(4))) float f32x4;

__device__ __forceinline__ float bf2f(unsigned short u){
    return __uint_as_float(((unsigned int)u) << 16);
}

// Exact 3-way truncation split: x == h + m + l exactly.
__device__ __forceinline__ void split3(float x, unsigned short& h,
                                       unsigned short& m, unsigned short& l){
    unsigned u = __float_as_uint(x);
    h = (unsigned short)(u >> 16);
    float r1 = x - __uint_as_float(u & 0xFFFF0000u);
    unsigned u1 = __float_as_uint(r1);
    m = (unsigned short)(u1 >> 16);
    float r2 = r1 - __uint_as_float(u1 & 0xFFFF0000u);
    l = (unsigned short)(__float_as_uint(r2) >> 16);
}

__global__ void split3_w(const float* __restrict__ src,
                         unsigned short* __restrict__ hi,
                         unsigned short* __restrict__ mi,
                         unsigned short* __restrict__ lo, int n4)
{
    int i = blockIdx.x * blockDim.x + threadIdx.x;
    int stride = gridDim.x * blockDim.x;
    for (; i < n4; i += stride) {
        float4 v = ((const float4*)src)[i];
        ushort4 h, m, l;
        split3(v.x, h.x, m.x, l.x); split3(v.y, h.y, m.y, l.y);
        split3(v.z, h.z, m.z, l.z); split3(v.w, h.w, m.w, l.w);
        ((ushort4*)hi)[i] = h;
        ((ushort4*)mi)[i] = m;
        ((ushort4*)lo)[i] = l;
    }
}

// 8-byte-granular LDS helpers for the MFMA kernel (LP=40 ushort rows = 80 B)
__device__ __forceinline__ void st8x2(unsigned short* p, int4 v){
    ((int2*)p)[0] = make_int2(v.x, v.y);
    ((int2*)p)[1] = make_int2(v.z, v.w);
}
__device__ __forceinline__ bf16x8 ld_frag(const unsigned short* p){
    union { bf16x8 v; ushort4 u[2]; } t;
    t.u[0] = *(const ushort4*)(p);
    t.u[1] = *(const ushort4*)(p + 4);
    return t.v;
}

// t=0 PLIF step (prev spikes all zero). Wave-per-(row,64-col-word) so the
// spike mask falls out of one __ballot. v math bit-identical to round-5/8
// step0: v = (brec[col] + curr[idx]) * decay, RN ops, no FMA contraction.
__global__ __launch_bounds__(256)
void step0_kernel(const float* __restrict__ curr0,
                  const float* __restrict__ brec,
                  const float* __restrict__ wlif,
                  float* __restrict__ vstate,
                  unsigned short* __restrict__ spk0,
                  unsigned long long* __restrict__ masks0)
{
    const float decay = 1.f / (1.f + expf(-wlif[0]));
    const int lane = threadIdx.x & 63;
    const int wid  = threadIdx.x >> 6;
    const int wtotal = gridDim.x * 4;
    const int NT = BNROWS * (H_DIM / 64);   // 32768 wave-tasks
    for (int task = blockIdx.x * 4 + wid; task < NT; task += wtotal) {
        int row = task >> 4, w = task & 15;
        int col = w * 64 + lane;
        size_t idx = (size_t)row * H_DIM + col;
        float c = curr0[idx];
        float v = __fmul_rn(__fadd_rn(brec[col], c), decay);
        bool s = (v - 1.0f) >= 0.0f;
        vstate[idx] = s ? 0.f : v;
        spk0[idx]   = s ? (unsigned short)0x3F80 : (unsigned short)0;
        unsigned long long bm = __ballot(s);
        if (lane == 0) masks0[task] = bm;
    }
}

// ======== fc1: fp32 VALU GEMM, single-buffered (round-7/8 proven). ========
template<int BM, int BN, int BK, int TM, int TN>
__global__ __launch_bounds__(256)
void gemm_fc1(const float* __restrict__ Ap,
              const float* __restrict__ Bp,
              int K, int ldc,
              const float* __restrict__ bias,
              float* __restrict__ Cout)
{
    constexpr int BMP = BM + 4;
    constexpr int BNP = BN + 4;
    __shared__ float smem[BK*BMP + BK*BNP];
    float* As = smem;
    float* Bs = smem + BK*BMP;

    const int tid = threadIdx.x;
    constexpr int TXN = BN / TN;
    const int tx = tid % TXN;
    const int ty = tid / TXN;
    const int bm0 = blockIdx.y * BM;
    const int bn0 = blockIdx.x * BN;

    constexpr int CPR = BK / 4;

    float acc[TM][TN];
#pragma unroll
    for (int i = 0; i < TM; ++i)
#pragma unroll
        for (int j = 0; j < TN; ++j) acc[i][j] = 0.f;

    for (int kt = 0; kt < K; kt += BK) {
        {
            constexpr int PT = (BM*BK/4)/256;
#pragma unroll
            for (int it = 0; it < PT; ++it) {
                int e   = it*256 + tid;
                int row = e / CPR;
                int c4  = e % CPR;
                float4 fv = *(const float4*)(Ap + (size_t)(bm0+row)*K + kt + c4*4);
                As[(c4*4+0)*BMP + row] = fv.x;
                As[(c4*4+1)*BMP + row] = fv.y;
                As[(c4*4+2)*BMP + row] = fv.z;
                As[(c4*4+3)*BMP + row] = fv.w;
            }
        }
        {
            constexpr int PT = (BN*BK/4)/256;
#pragma unroll
            for (int it = 0; it < PT; ++it) {
                int e   = it*256 + tid;
                int row = e / CPR;
                int c4  = e % CPR;
                float4 fv = *(const float4*)(Bp + (size_t)(bn0+row)*K + kt + c4*4);
                Bs[(c4*4+0)*BNP + row] = fv.x;
                Bs[(c4*4+1)*BNP + row] = fv.y;
                Bs[(c4*4+2)*BNP + row] = fv.z;
                Bs[(c4*4+3)*BNP + row] = fv.w;
            }
        }
        __syncthreads();
#pragma unroll
        for (int k = 0; k < BK; ++k) {
            float a[TM], b[TN];
            float4 t0 = *(const float4*)&As[k*BMP + ty*8];
            float4 t1 = *(const float4*)&As[k*BMP + ty*8 + 4];
            a[0]=t0.x; a[1]=t0.y; a[2]=t0.z; a[3]=t0.w;
            a[4]=t1.x; a[5]=t1.y; a[6]=t1.z; a[7]=t1.w;
            float4 u0 = *(const float4*)&Bs[k*BNP + tx*4];
            float4 u1 = *(const float4*)&Bs[k*BNP + 64 + tx*4];
            b[0]=u0.x; b[1]=u0.y; b[2]=u0.z; b[3]=u0.w;
            b[4]=u1.x; b[5]=u1.y; b[6]=u1.z; b[7]=u1.w;
#pragma unroll
            for (int i = 0; i < TM; ++i)
#pragma unroll
                for (int j = 0; j < TN; ++j)
                    acc[i][j] = fmaf(a[i], b[j], acc[i][j]);
        }
        __syncthreads();
    }

#pragma unroll
    for (int i = 0; i < TM; ++i) {
        int m = bm0 + ty*TM + i;
        int n0 = bn0 + tx*4;
        int n1 = bn0 + 64 + tx*4;
        float4 bv0 = *(const float4*)&bias[n0];
        float4 bv1 = *(const float4*)&bias[n1];
        float4 o0, o1;
        o0.x = acc[i][0] + bv0.x; o0.y = acc[i][1] + bv0.y;
        o0.z = acc[i][2] + bv0.z; o0.w = acc[i][3] + bv0.w;
        o1.x = acc[i][4] + bv1.x; o1.y = acc[i][5] + bv1.y;
        o1.z = acc[i][6] + bv1.z; o1.w = acc[i][7] + bv1.w;
        *(float4*)&Cout[(size_t)m*ldc + n0] = o0;
        *(float4*)&Cout[(size_t)m*ldc + n1] = o1;
    }
}

// ======== rec step: sparse ordered gather-sum, mask-fed, 4-deep pipelined.
// out[m][n] = sum_{k ascending, spike} Wrec[n][k] — identical add sequence to
// round-8's passing kernel (skip-zero is exact; acc never -0). Masks come from
// the previous step's ballot (identical bits to the ushort spikes).
__global__ __launch_bounds__(256)
void rec_sparse(const unsigned long long* __restrict__ masks_prev, // [2048][16]
                const float* __restrict__ Wrec,     // [H][H] row-major
                const float* __restrict__ brec,
                const float* __restrict__ curr_t,
                const float* __restrict__ wlif,
                float* __restrict__ vstate,
                unsigned short* __restrict__ spk_out,
                unsigned long long* __restrict__ masks_out)
{
    constexpr int BM = 32, BN = 64, BK = 64, BNP = BN + 4;
    __shared__ float Bs[BK * BNP];                      // 17.4 KB
    __shared__ unsigned long long msk[BM * 16];         // 4 KB

    const int tid  = threadIdx.x;
    const int lane = tid & 63;
    const int wid  = tid >> 6;          // 4 waves
    const int bn0  = blockIdx.x * BN;   // 16 n-blocks
    const int bm0  = blockIdx.y * BM;   // 64 m-blocks
    const int r0   = wid * 8;           // 8 rows per wave

    // preload this block's 32x16 mask words (4 KB, one int4 per thread)
    ((int4*)msk)[tid] = ((const int4*)(masks_prev + (size_t)bm0 * 16))[tid];

    float acc[8];
#pragma unroll
    for (int i = 0; i < 8; ++i) acc[i] = 0.f;

    for (int kt = 0; kt < H_DIM; kt += BK) {
        // stage Bs[k][n] = Wrec[bn0+n][kt+k]
#pragma unroll
        for (int it = 0; it < (BN*BK/4)/256; ++it) {   // 4 iters
            int e   = it*256 + tid;
            int row = e >> 4;
            int c4  = e & 15;
            float4 fv = *(const float4*)(Wrec + (size_t)(bn0+row)*H_DIM + kt + c4*4);
            Bs[(c4*4+0)*BNP + row] = fv.x;
            Bs[(c4*4+1)*BNP + row] = fv.y;
            Bs[(c4*4+2)*BNP + row] = fv.z;
            Bs[(c4*4+3)*BNP + row] = fv.w;
        }
        __syncthreads();
        const int wslot = kt >> 6;
#pragma unroll
        for (int i = 0; i < 8; ++i) {
            unsigned long long mv = msk[(r0 + i) * 16 + wslot];
            unsigned lo = __builtin_amdgcn_readfirstlane((unsigned)mv);
            unsigned hi = __builtin_amdgcn_readfirstlane((unsigned)(mv >> 32));
            unsigned long long m = ((unsigned long long)hi << 32) | lo;
            while (m) {
                // gather up to 4 ascending indices, issue 4 independent LDS
                // reads, then add in ascending order (bit-exact chain)
                int k0 = __builtin_ctzll(m); m &= m - 1;
                float w0 = Bs[k0 * BNP + lane];
                if (!m) { acc[i] += w0; break; }
                int k1 = __builtin_ctzll(m); m &= m - 1;
                float w1 = Bs[k1 * BNP + lane];
                if (!m) { acc[i] += w0; acc[i] += w1; break; }
                int k2 = __builtin_ctzll(m); m &= m - 1;
                float w2 = Bs[k2 * BNP + lane];
                if (!m) { acc[i] += w0; acc[i] += w1; acc[i] += w2; break; }
                int k3 = __builtin_ctzll(m); m &= m - 1;
                float w3 = Bs[k3 * BNP + lane];
                acc[i] += w0; acc[i] += w1; acc[i] += w2; acc[i] += w3;
            }
        }
        __syncthreads();
    }

    const float decay = 1.f / (1.f + expf(-wlif[0]));
    const int n = bn0 + lane;
    const float bv = brec[n];
#pragma unroll
    for (int i = 0; i < 8; ++i) {
        int mrow = bm0 + r0 + i;
        size_t idx = (size_t)mrow * H_DIM + n;
        float inp = acc[i] + bv + curr_t[idx];
        float vv  = vstate[idx];
        vv = vv + (inp - vv) * decay;
        bool s = (vv - 1.0f) >= 0.0f;
        vstate[idx]  = s ? 0.0f : vv;
        spk_out[idx] = s ? (unsigned short)0x3F80 : (unsigned short)0;
        unsigned long long bm = __ballot(s);
        if (lane == 0) masks_out[(size_t)mrow * 16 + blockIdx.x] = bm;
    }
}

// ======== MFMA GEMM for fc2 only (feeds BN; loose tolerance) ========
template<int BM, int BN, int WM, int WN, int MI, int NI>
__global__ __launch_bounds__(256)
void mfma_fc2(const unsigned short* __restrict__ Aptr,
              const unsigned short* __restrict__ Bhi,
              const unsigned short* __restrict__ Bmi,
              int K,
              const float* __restrict__ bias,
              float* __restrict__ Cout, int ldc,
              float* __restrict__ partials)
{
    constexpr int LP  = 40;
    constexpr int APL = BM * LP;
    constexpr int BPL = BN * LP;
    __shared__ alignas(16) unsigned short sA[APL];
    __shared__ alignas(16) unsigned short sB[2 * BPL];

    const int nwg = gridDim.x * gridDim.y;
    const int f   = blockIdx.y * gridDim.x + blockIdx.x;
    const int q   = nwg >> 3;
    const int lg  = (f & 7) * q + (f >> 3);
    const int bn0  = (lg % gridDim.x) * BN;
    const int mblk = lg / gridDim.x;
    const int bm0  = mblk * BM;

    const int tid  = threadIdx.x;
    const int lane = tid & 63;
    const int wid  = tid >> 6;
    const int wr   = wid / WN;
    const int wc   = wid % WN;
    const int lr   = lane & 15;
    const int lk   = lane >> 4;

    f32x4 accB[MI][NI], accS[MI][NI];
#pragma unroll
    for (int i = 0; i < MI; ++i)
#pragma unroll
        for (int j = 0; j < NI; ++j) {
            accB[i][j] = (f32x4){0.f, 0.f, 0.f, 0.f};
            accS[i][j] = (f32x4){0.f, 0.f, 0.f, 0.f};
        }

    for (int kt = 0; kt < K; kt += 32) {
#pragma unroll
        for (int p = 0; p < BM / 64; ++p) {
            int e = p * 256 + tid;
            int row = e >> 2, c8 = e & 3;
            int4 v = *(const int4*)(Aptr + (size_t)(bm0 + row) * K + kt + c8 * 8);
            st8x2(&sA[row * LP + c8 * 8], v);
        }
#pragma unroll
        for (int p = 0; p < BN / 64; ++p) {
            int e = p * 256 + tid;
            int row = e >> 2, c8 = e & 3;
            size_t g = (size_t)(bn0 + row) * K + kt + c8 * 8;
            st8x2(&sB[row * LP + c8 * 8],       *(const int4*)(Bhi + g));
            st8x2(&sB[BPL + row * LP + c8 * 8], *(const int4*)(Bmi + g));
        }
        __syncthreads();

        bf16x8 af[MI], b0[NI], b1[NI];
#pragma unroll
        for (int i = 0; i < MI; ++i) {
            int r = wr * MI * 16 + i * 16 + lr;
            af[i] = ld_frag(&sA[r * LP + lk * 8]);
        }
#pragma unroll
        for (int j = 0; j < NI; ++j) {
            int r = wc * NI * 16 + j * 16 + lr;
            b0[j] = ld_frag(&sB[r * LP + lk * 8]);
            b1[j] = ld_frag(&sB[BPL + r * LP + lk * 8]);
        }
#pragma unroll
        for (int i = 0; i < MI; ++i)
#pragma unroll
            for (int j = 0; j < NI; ++j) {
                accB[i][j] = __builtin_amdgcn_mfma_f32_16x16x32_bf16(af[i], b0[j], accB[i][j], 0, 0, 0);
                accS[i][j] = __builtin_amdgcn_mfma_f32_16x16x32_bf16(af[i], b1[j], accS[i][j], 0, 0, 0);
            }
        __syncthreads();
    }

    float csum[NI], csq[NI];
#pragma unroll
    for (int j = 0; j < NI; ++j) { csum[j] = 0.f; csq[j] = 0.f; }
#pragma unroll
    for (int i = 0; i < MI; ++i)
#pragma unroll
        for (int j = 0; j < NI; ++j) {
            int col = bn0 + wc * NI * 16 + j * 16 + lr;
            float bv = bias[col];
#pragma unroll
            for (int r = 0; r < 4; ++r) {
                int row = bm0 + wr * MI * 16 + i * 16 + lk * 4 + r;
                float o = (accB[i][j][r] + accS[i][j][r]) + bv;
                Cout[(size_t)row * ldc + col] = o;
                csum[j] += o;
                csq[j]  += o * o;
            }
        }
    __syncthreads();
    float* redS = (float*)sA;
    float* redQ = (float*)sB;
    const int slot = wr * 4 + lk;
#pragma unroll
    for (int j = 0; j < NI; ++j) {
        int c = wc * NI * 16 + j * 16 + lr;
        redS[slot * BN + c] = csum[j];
        redQ[slot * BN + c] = csq[j];
    }
    __syncthreads();
    if (tid < BN) {
        float s = 0.f, qq = 0.f;
        for (int sl = 0; sl < WM * 4; ++sl) { s += redS[sl * BN + tid]; qq += redQ[sl * BN + tid]; }
        partials[((size_t)mblk * 2 + 0) * O_DIM + bn0 + tid] = s;
        partials[((size_t)mblk * 2 + 1) * O_DIM + bn0 + tid] = qq;
    }
}

__global__ void bn_finalize(const float* __restrict__ partials,
                            const float* __restrict__ gamma,
                            const float* __restrict__ beta,
                            float* __restrict__ scsh, int nmblk)
{
    int o = threadIdx.x;   // 512 threads
    float s = 0.f, q = 0.f;
    for (int mb = 0; mb < nmblk; ++mb) {
        s += partials[((size_t)mb*2 + 0)*O_DIM + o];
        q += partials[((size_t)mb*2 + 1)*O_DIM + o];
    }
    const float invn = 1.f / (float)TBN_DIM;
    float mean = s * invn;
    float var  = q * invn - mean*mean;
    float sc   = gamma[o] * rsqrtf(var + 1e-5f);
    scsh[o]        = sc;
    scsh[O_DIM+o]  = beta[o] - mean*sc;
}

__global__ void bn_apply(float* __restrict__ out, const float* __restrict__ scsh)
{
    const size_t total4 = (size_t)TBN_DIM * O_DIM / 4;
    const float4* sc4 = (const float4*)scsh;
    const float4* sh4 = (const float4*)(scsh + O_DIM);
    size_t stride = (size_t)gridDim.x * blockDim.x;
    for (size_t idx = (size_t)blockIdx.x*blockDim.x + threadIdx.x; idx < total4; idx += stride) {
        float4 v = ((float4*)out)[idx];
        int c4 = (int)(idx & (O_DIM/4 - 1));
        float4 sc = sc4[c4], sh = sh4[c4];
        v.x = v.x*sc.x + sh.x;
        v.y = v.y*sc.y + sh.y;
        v.z = v.z*sc.z + sh.z;
        v.w = v.w*sc.w + sh.w;
        ((float4*)out)[idx] = v;
    }
}

extern "C" void kernel_launch(void* const* d_in, const int* in_sizes, int n_in,
                              void* d_out, int out_size, void* d_ws, size_t ws_size,
                              hipStream_t stream) {
    const float* x     = (const float*)d_in[0];
    const float* W1    = (const float*)d_in[1];
    const float* b1    = (const float*)d_in[2];
    const float* Wrec  = (const float*)d_in[3];
    const float* brec  = (const float*)d_in[4];
    const float* wlif  = (const float*)d_in[5];
    const float* W2    = (const float*)d_in[6];
    const float* b2    = (const float*)d_in[7];
    const float* gamma = (const float*)d_in[8];
    const float* beta  = (const float*)d_in[9];
    float* out = (float*)d_out;

    // ws layout (~415.5 MB, within round-1's proven 417.3 MB footprint)
    char* w = (char*)d_ws;
    float*          curr   = (float*)w;                            // 256 MB
    unsigned short* spk    = (unsigned short*)(w + 268435456);     // 128 MB, slots 0..31
    float*          vstate = (float*)(w + 402653184);              // 8 MB
    unsigned short* w2p    = (unsigned short*)(w + 411041792);     // W2 planes, 3 MB
    unsigned long long* mring = (unsigned long long*)(w + 414187520); // 2 x 256 KB
    float* partials = curr;                 // overlay: curr dead after scan
    float* scsh     = curr + 512 * 2 * O_DIM;

    const int W2N = O_DIM * H_DIM;          // 524288
    const size_t MWORDS = (size_t)BNROWS * 16;   // 32768 words per slot

    // fc1: curr = x @ W1^T + b1   (proven frozen-chain fp32 engine)
    gemm_fc1<128,128,16,8,8>
        <<<dim3(H_DIM/128, TBN_DIM/128), 256, 0, stream>>>(
            x, W1, C_DIM, H_DIM, b1, curr);

    // t=0 elementwise (bit-exact), also emits mask words into ring slot 0
    step0_kernel<<<dim3(2048), 256, 0, stream>>>(curr, brec, wlif, vstate, spk,
                                                 mring);

    // recurrent scan t=1..31: mask-fed sparse gather, 4-deep read pipeline
    for (int t = 1; t < T_STEPS; ++t) {
        const unsigned long long* mprev = mring + ((t - 1) & 1) * MWORDS;
        unsigned long long*       mout  = mring + (t & 1) * MWORDS;
        rec_sparse<<<dim3(H_DIM/64, BNROWS/32), 256, 0, stream>>>(
            mprev, Wrec, brec,
            curr + (size_t)t * BNROWS * H_DIM, wlif, vstate,
            spk + (size_t)t * BNROWS * H_DIM, mout);
    }

    // fc2 (BN-only consumer): 2-plane bf16 MFMA + fused BN partials
    split3_w<<<dim3(256), 256, 0, stream>>>(W2, w2p, w2p + W2N, w2p + 2 * W2N, W2N / 4);
    mfma_fc2<128, 128, 2, 2, 4, 4>
        <<<dim3(O_DIM/128, TBN_DIM/128), 256, 0, stream>>>(
            spk, w2p, w2p + W2N, H_DIM, b2, out, O_DIM, partials);

    bn_finalize<<<1, O_DIM, 0, stream>>>(partials, gamma, beta, scsh, TBN_DIM/128);
    bn_apply<<<2048, 256, 0, stream>>>(out, scsh);
}

// Round 10
// 2855.300 us; speedup vs baseline: 1.4300x; 1.1589x over previous
//
#include <hip/hip_runtime.h>
#include <cstdint>
#include <cstddef>

#define T_STEPS 32
#define BNROWS  2048     // B*N
#define C_DIM   512
#define H_DIM   1024
#define O_DIM   512
#define TBN_DIM 65536    // T_STEPS*BNROWS

typedef __attribute__((ext_vector_type(8))) short bf16x8;
typedef __attribute__((ext_vector_type(4))) float f32x4;

__device__ __forceinline__ float bf2f(unsigned short u){
    return __uint_as_float(((unsigned int)u) << 16);
}

// Exact 3-way truncation split: x == h + m + l exactly.
__device__ __forceinline__ void split3(float x, unsigned short& h,
                                       unsigned short& m, unsigned short& l){
    unsigned u = __float_as_uint(x);
    h = (unsigned short)(u >> 16);
    float r1 = x - __uint_as_float(u & 0xFFFF0000u);
    unsigned u1 = __float_as_uint(r1);
    m = (unsigned short)(u1 >> 16);
    float r2 = r1 - __uint_as_float(u1 & 0xFFFF0000u);
    l = (unsigned short)(__float_as_uint(r2) >> 16);
}

__global__ void split3_w(const float* __restrict__ src,
                         unsigned short* __restrict__ hi,
                         unsigned short* __restrict__ mi,
                         unsigned short* __restrict__ lo, int n4)
{
    int i = blockIdx.x * blockDim.x + threadIdx.x;
    int stride = gridDim.x * blockDim.x;
    for (; i < n4; i += stride) {
        float4 v = ((const float4*)src)[i];
        ushort4 h, m, l;
        split3(v.x, h.x, m.x, l.x); split3(v.y, h.y, m.y, l.y);
        split3(v.z, h.z, m.z, l.z); split3(v.w, h.w, m.w, l.w);
        ((ushort4*)hi)[i] = h;
        ((ushort4*)mi)[i] = m;
        ((ushort4*)lo)[i] = l;
    }
}

// 8-byte-granular LDS helpers for the MFMA kernel (LP=40 ushort rows = 80 B)
__device__ __forceinline__ void st8x2(unsigned short* p, int4 v){
    ((int2*)p)[0] = make_int2(v.x, v.y);
    ((int2*)p)[1] = make_int2(v.z, v.w);
}
__device__ __forceinline__ bf16x8 ld_frag(const unsigned short* p){
    union { bf16x8 v; ushort4 u[2]; } t;
    t.u[0] = *(const ushort4*)(p);
    t.u[1] = *(const ushort4*)(p + 4);
    return t.v;
}

// WrecT[k][n] = Wrec[n][k]  (one-time 4 MB transpose)
__global__ void wrec_transpose(const float* __restrict__ src,
                               float* __restrict__ dst)
{
    __shared__ float tile[32][33];
    const int bx = blockIdx.x * 32, by = blockIdx.y * 32;
    const int tx = threadIdx.x & 31, ty = threadIdx.x >> 5;   // 32x8
#pragma unroll
    for (int r = 0; r < 32; r += 8)
        tile[ty + r][tx] = src[(size_t)(by + ty + r) * H_DIM + bx + tx];
    __syncthreads();
#pragma unroll
    for (int r = 0; r < 32; r += 8)
        dst[(size_t)(bx + ty + r) * H_DIM + by + tx] = tile[tx][ty + r];
}

// t=0 PLIF step (prev spikes all zero). v math bit-identical to round-5..9.
__global__ __launch_bounds__(256)
void step0_kernel(const float* __restrict__ curr0,
                  const float* __restrict__ brec,
                  const float* __restrict__ wlif,
                  float* __restrict__ vstate,
                  unsigned short* __restrict__ spk0,
                  unsigned long long* __restrict__ masks0)
{
    const float decay = 1.f / (1.f + expf(-wlif[0]));
    const int lane = threadIdx.x & 63;
    const int wid  = threadIdx.x >> 6;
    const int wtotal = gridDim.x * 4;
    const int NT = BNROWS * (H_DIM / 64);   // 32768 wave-tasks
    for (int task = blockIdx.x * 4 + wid; task < NT; task += wtotal) {
        int row = task >> 4, w = task & 15;
        int col = w * 64 + lane;
        size_t idx = (size_t)row * H_DIM + col;
        float c = curr0[idx];
        float v = __fmul_rn(__fadd_rn(brec[col], c), decay);
        bool s = (v - 1.0f) >= 0.0f;
        vstate[idx] = s ? 0.f : v;
        spk0[idx]   = s ? (unsigned short)0x3F80 : (unsigned short)0;
        unsigned long long bm = __ballot(s);
        if (lane == 0) masks0[task] = bm;
    }
}

// ======== fc1: fp32 VALU GEMM, single-buffered (round-7/8/9 proven). ========
template<int BM, int BN, int BK, int TM, int TN>
__global__ __launch_bounds__(256)
void gemm_fc1(const float* __restrict__ Ap,
              const float* __restrict__ Bp,
              int K, int ldc,
              const float* __restrict__ bias,
              float* __restrict__ Cout)
{
    constexpr int BMP = BM + 4;
    constexpr int BNP = BN + 4;
    __shared__ float smem[BK*BMP + BK*BNP];
    float* As = smem;
    float* Bs = smem + BK*BMP;

    const int tid = threadIdx.x;
    constexpr int TXN = BN / TN;
    const int tx = tid % TXN;
    const int ty = tid / TXN;
    const int bm0 = blockIdx.y * BM;
    const int bn0 = blockIdx.x * BN;

    constexpr int CPR = BK / 4;

    float acc[TM][TN];
#pragma unroll
    for (int i = 0; i < TM; ++i)
#pragma unroll
        for (int j = 0; j < TN; ++j) acc[i][j] = 0.f;

    for (int kt = 0; kt < K; kt += BK) {
        {
            constexpr int PT = (BM*BK/4)/256;
#pragma unroll
            for (int it = 0; it < PT; ++it) {
                int e   = it*256 + tid;
                int row = e / CPR;
                int c4  = e % CPR;
                float4 fv = *(const float4*)(Ap + (size_t)(bm0+row)*K + kt + c4*4);
                As[(c4*4+0)*BMP + row] = fv.x;
                As[(c4*4+1)*BMP + row] = fv.y;
                As[(c4*4+2)*BMP + row] = fv.z;
                As[(c4*4+3)*BMP + row] = fv.w;
            }
        }
        {
            constexpr int PT = (BN*BK/4)/256;
#pragma unroll
            for (int it = 0; it < PT; ++it) {
                int e   = it*256 + tid;
                int row = e / CPR;
                int c4  = e % CPR;
                float4 fv = *(const float4*)(Bp + (size_t)(bn0+row)*K + kt + c4*4);
                Bs[(c4*4+0)*BNP + row] = fv.x;
                Bs[(c4*4+1)*BNP + row] = fv.y;
                Bs[(c4*4+2)*BNP + row] = fv.z;
                Bs[(c4*4+3)*BNP + row] = fv.w;
            }
        }
        __syncthreads();
#pragma unroll
        for (int k = 0; k < BK; ++k) {
            float a[TM], b[TN];
            float4 t0 = *(const float4*)&As[k*BMP + ty*8];
            float4 t1 = *(const float4*)&As[k*BMP + ty*8 + 4];
            a[0]=t0.x; a[1]=t0.y; a[2]=t0.z; a[3]=t0.w;
            a[4]=t1.x; a[5]=t1.y; a[6]=t1.z; a[7]=t1.w;
            float4 u0 = *(const float4*)&Bs[k*BNP + tx*4];
            float4 u1 = *(const float4*)&Bs[k*BNP + 64 + tx*4];
            b[0]=u0.x; b[1]=u0.y; b[2]=u0.z; b[3]=u0.w;
            b[4]=u1.x; b[5]=u1.y; b[6]=u1.z; b[7]=u1.w;
#pragma unroll
            for (int i = 0; i < TM; ++i)
#pragma unroll
                for (int j = 0; j < TN; ++j)
                    acc[i][j] = fmaf(a[i], b[j], acc[i][j]);
        }
        __syncthreads();
    }

#pragma unroll
    for (int i = 0; i < TM; ++i) {
        int m = bm0 + ty*TM + i;
        int n0 = bn0 + tx*4;
        int n1 = bn0 + 64 + tx*4;
        float4 bv0 = *(const float4*)&bias[n0];
        float4 bv1 = *(const float4*)&bias[n1];
        float4 o0, o1;
        o0.x = acc[i][0] + bv0.x; o0.y = acc[i][1] + bv0.y;
        o0.z = acc[i][2] + bv0.z; o0.w = acc[i][3] + bv0.w;
        o1.x = acc[i][4] + bv1.x; o1.y = acc[i][5] + bv1.y;
        o1.z = acc[i][6] + bv1.z; o1.w = acc[i][7] + bv1.w;
        *(float4*)&Cout[(size_t)m*ldc + n0] = o0;
        *(float4*)&Cout[(size_t)m*ldc + n1] = o1;
    }
}

// Morton spread: 16 bits -> every 4th bit of a 64-bit word
__device__ __forceinline__ unsigned long long spread4(unsigned long long x){
    x &= 0xFFFFull;
    x = (x | (x << 24)) & 0x000000FF000000FFull;
    x = (x | (x << 12)) & 0x000F000F000F000Full;
    x = (x | (x << 6 )) & 0x0303030303030303ull;
    x = (x | (x << 3 )) & 0x1111111111111111ull;
    return x;
}

// ======== rec step v2: mask-fed sparse gather, b128 x 4-col, branchless quads.
// out[m][n] = sum_{k ascending, spike} Wrec[n][k]. Chain bit-identical to the
// dense ascending-k chain: skip-zero exact; fmaf(w,1,acc)==acc+w;
// fmaf(w,0,acc)==acc (acc never -0). Uniform trip counts, no divergence.
__global__ __launch_bounds__(256)
void rec_sparse(const unsigned long long* __restrict__ masks_prev, // [2048][16]
                const float* __restrict__ WrecT,    // [k][n] transposed
                const float* __restrict__ brec,
                const float* __restrict__ curr_t,
                const float* __restrict__ wlif,
                float* __restrict__ vstate,
                unsigned short* __restrict__ spk_out,
                unsigned long long* __restrict__ masks_out)
{
    constexpr int BM = 32, BN = 256, BK = 64, BNP = BN + 4;
    __shared__ float Bs[BK * BNP];                      // 66.6 KB
    __shared__ unsigned long long msk[BM * 16];         // 4 KB

    const int tid  = threadIdx.x;
    const int lane = tid & 63;
    const int wid  = tid >> 6;          // 4 waves
    const int bn0  = blockIdx.x * BN;   // 4 n-blocks
    const int bm0  = blockIdx.y * BM;   // 64 m-blocks
    const int r0   = wid * 8;           // 8 rows per wave
    const unsigned long long MSB = 0x8000000000000000ull;

    // preload this block's 32x16 mask words (4 KB, one int4 per thread)
    ((int4*)msk)[tid] = ((const int4*)(masks_prev + (size_t)bm0 * 16))[tid];

    float acc[8][4];
#pragma unroll
    for (int i = 0; i < 8; ++i)
#pragma unroll
        for (int j = 0; j < 4; ++j) acc[i][j] = 0.f;

    for (int kt = 0; kt < H_DIM; kt += BK) {
        // stage Bs[k][n] = WrecT[kt+k][bn0+n]  (contiguous float4 both sides)
#pragma unroll
        for (int it = 0; it < 16; ++it) {
            int e  = it * 256 + tid;        // 0..4095
            int k  = e >> 6;
            int n4 = e & 63;
            float4 fv = *(const float4*)(WrecT + (size_t)(kt + k) * H_DIM + bn0 + n4 * 4);
            *(float4*)&Bs[k * BNP + n4 * 4] = fv;
        }
        __syncthreads();
        const int wslot = kt >> 6;
#pragma unroll
        for (int i = 0; i < 8; ++i) {
            unsigned long long mv = msk[(r0 + i) * 16 + wslot];
            unsigned lo = __builtin_amdgcn_readfirstlane((unsigned)mv);
            unsigned hi = __builtin_amdgcn_readfirstlane((unsigned)(mv >> 32));
            unsigned long long m = ((unsigned long long)hi << 32) | lo;
            int pc = __popcll(m);
            float a0 = acc[i][0], a1 = acc[i][1], a2 = acc[i][2], a3 = acc[i][3];
            for (int s = 0; s < pc; s += 4) {
                int k0 = __builtin_ctzll(m | MSB); m &= m - 1;
                int k1 = __builtin_ctzll(m | MSB); m &= m - 1;
                int k2 = __builtin_ctzll(m | MSB); m &= m - 1;
                int k3 = __builtin_ctzll(m | MSB); m &= m - 1;
                float4 w0 = *(const float4*)&Bs[k0 * BNP + lane * 4];
                float4 w1 = *(const float4*)&Bs[k1 * BNP + lane * 4];
                float4 w2 = *(const float4*)&Bs[k2 * BNP + lane * 4];
                float4 w3 = *(const float4*)&Bs[k3 * BNP + lane * 4];
                float s1v = (s + 1 < pc) ? 1.f : 0.f;
                float s2v = (s + 2 < pc) ? 1.f : 0.f;
                float s3v = (s + 3 < pc) ? 1.f : 0.f;
                a0 += w0.x; a1 += w0.y; a2 += w0.z; a3 += w0.w;
                a0 = fmaf(w1.x, s1v, a0); a1 = fmaf(w1.y, s1v, a1);
                a2 = fmaf(w1.z, s1v, a2); a3 = fmaf(w1.w, s1v, a3);
                a0 = fmaf(w2.x, s2v, a0); a1 = fmaf(w2.y, s2v, a1);
                a2 = fmaf(w2.z, s2v, a2); a3 = fmaf(w2.w, s2v, a3);
                a0 = fmaf(w3.x, s3v, a0); a1 = fmaf(w3.y, s3v, a1);
                a2 = fmaf(w3.z, s3v, a2); a3 = fmaf(w3.w, s3v, a3);
            }
            acc[i][0] = a0; acc[i][1] = a1; acc[i][2] = a2; acc[i][3] = a3;
        }
        __syncthreads();
    }

    // epilogue: PLIF update for 4 cols per lane, verbatim expressions
    const float decay = 1.f / (1.f + expf(-wlif[0]));
    const int n0 = bn0 + lane * 4;
    float4 bv = *(const float4*)&brec[n0];
#pragma unroll
    for (int i = 0; i < 8; ++i) {
        int mrow = bm0 + r0 + i;
        size_t idx = (size_t)mrow * H_DIM + n0;
        float4 cv = *(const float4*)&curr_t[idx];
        float4 vv = *(const float4*)&vstate[idx];
        float inp0 = acc[i][0] + bv.x + cv.x;
        float inp1 = acc[i][1] + bv.y + cv.y;
        float inp2 = acc[i][2] + bv.z + cv.z;
        float inp3 = acc[i][3] + bv.w + cv.w;
        float v0 = vv.x + (inp0 - vv.x) * decay;
        float v1 = vv.y + (inp1 - vv.y) * decay;
        float v2 = vv.z + (inp2 - vv.z) * decay;
        float v3 = vv.w + (inp3 - vv.w) * decay;
        bool s0 = (v0 - 1.0f) >= 0.0f, s1 = (v1 - 1.0f) >= 0.0f;
        bool s2 = (v2 - 1.0f) >= 0.0f, s3 = (v3 - 1.0f) >= 0.0f;
        float4 vo; vo.x = s0 ? 0.f : v0; vo.y = s1 ? 0.f : v1;
        vo.z = s2 ? 0.f : v2; vo.w = s3 ? 0.f : v3;
        ushort4 sp;
        sp.x = s0 ? 0x3F80 : 0; sp.y = s1 ? 0x3F80 : 0;
        sp.z = s2 ? 0x3F80 : 0; sp.w = s3 ? 0x3F80 : 0;
        *(float4*)&vstate[idx]   = vo;
        *(ushort4*)&spk_out[idx] = sp;
        // masks: bit (4t+j) of word w == spike of col 64w+4t+j
        unsigned long long b0 = __ballot(s0);
        unsigned long long b1 = __ballot(s1);
        unsigned long long b2 = __ballot(s2);
        unsigned long long b3 = __ballot(s3);
        if (lane == 0) {
#pragma unroll
            for (int w = 0; w < 4; ++w) {
                unsigned long long word =
                    spread4(b0 >> (16 * w)) | (spread4(b1 >> (16 * w)) << 1) |
                    (spread4(b2 >> (16 * w)) << 2) | (spread4(b3 >> (16 * w)) << 3);
                masks_out[(size_t)mrow * 16 + blockIdx.x * 4 + w] = word;
            }
        }
    }
}

// ======== MFMA GEMM for fc2 only (feeds BN; loose tolerance) ========
template<int BM, int BN, int WM, int WN, int MI, int NI>
__global__ __launch_bounds__(256)
void mfma_fc2(const unsigned short* __restrict__ Aptr,
              const unsigned short* __restrict__ Bhi,
              const unsigned short* __restrict__ Bmi,
              int K,
              const float* __restrict__ bias,
              float* __restrict__ Cout, int ldc,
              float* __restrict__ partials)
{
    constexpr int LP  = 40;
    constexpr int APL = BM * LP;
    constexpr int BPL = BN * LP;
    __shared__ alignas(16) unsigned short sA[APL];
    __shared__ alignas(16) unsigned short sB[2 * BPL];

    const int nwg = gridDim.x * gridDim.y;
    const int f   = blockIdx.y * gridDim.x + blockIdx.x;
    const int q   = nwg >> 3;
    const int lg  = (f & 7) * q + (f >> 3);
    const int bn0  = (lg % gridDim.x) * BN;
    const int mblk = lg / gridDim.x;
    const int bm0  = mblk * BM;

    const int tid  = threadIdx.x;
    const int lane = tid & 63;
    const int wid  = tid >> 6;
    const int wr   = wid / WN;
    const int wc   = wid % WN;
    const int lr   = lane & 15;
    const int lk   = lane >> 4;

    f32x4 accB[MI][NI], accS[MI][NI];
#pragma unroll
    for (int i = 0; i < MI; ++i)
#pragma unroll
        for (int j = 0; j < NI; ++j) {
            accB[i][j] = (f32x4){0.f, 0.f, 0.f, 0.f};
            accS[i][j] = (f32x4){0.f, 0.f, 0.f, 0.f};
        }

    for (int kt = 0; kt < K; kt += 32) {
#pragma unroll
        for (int p = 0; p < BM / 64; ++p) {
            int e = p * 256 + tid;
            int row = e >> 2, c8 = e & 3;
            int4 v = *(const int4*)(Aptr + (size_t)(bm0 + row) * K + kt + c8 * 8);
            st8x2(&sA[row * LP + c8 * 8], v);
        }
#pragma unroll
        for (int p = 0; p < BN / 64; ++p) {
            int e = p * 256 + tid;
            int row = e >> 2, c8 = e & 3;
            size_t g = (size_t)(bn0 + row) * K + kt + c8 * 8;
            st8x2(&sB[row * LP + c8 * 8],       *(const int4*)(Bhi + g));
            st8x2(&sB[BPL + row * LP + c8 * 8], *(const int4*)(Bmi + g));
        }
        __syncthreads();

        bf16x8 af[MI], b0[NI], b1[NI];
#pragma unroll
        for (int i = 0; i < MI; ++i) {
            int r = wr * MI * 16 + i * 16 + lr;
            af[i] = ld_frag(&sA[r * LP + lk * 8]);
        }
#pragma unroll
        for (int j = 0; j < NI; ++j) {
            int r = wc * NI * 16 + j * 16 + lr;
            b0[j] = ld_frag(&sB[r * LP + lk * 8]);
            b1[j] = ld_frag(&sB[BPL + r * LP + lk * 8]);
        }
#pragma unroll
        for (int i = 0; i < MI; ++i)
#pragma unroll
            for (int j = 0; j < NI; ++j) {
                accB[i][j] = __builtin_amdgcn_mfma_f32_16x16x32_bf16(af[i], b0[j], accB[i][j], 0, 0, 0);
                accS[i][j] = __builtin_amdgcn_mfma_f32_16x16x32_bf16(af[i], b1[j], accS[i][j], 0, 0, 0);
            }
        __syncthreads();
    }

    float csum[NI], csq[NI];
#pragma unroll
    for (int j = 0; j < NI; ++j) { csum[j] = 0.f; csq[j] = 0.f; }
#pragma unroll
    for (int i = 0; i < MI; ++i)
#pragma unroll
        for (int j = 0; j < NI; ++j) {
            int col = bn0 + wc * NI * 16 + j * 16 + lr;
            float bv = bias[col];
#pragma unroll
            for (int r = 0; r < 4; ++r) {
                int row = bm0 + wr * MI * 16 + i * 16 + lk * 4 + r;
                float o = (accB[i][j][r] + accS[i][j][r]) + bv;
                Cout[(size_t)row * ldc + col] = o;
                csum[j] += o;
                csq[j]  += o * o;
            }
        }
    __syncthreads();
    float* redS = (float*)sA;
    float* redQ = (float*)sB;
    const int slot = wr * 4 + lk;
#pragma unroll
    for (int j = 0; j < NI; ++j) {
        int c = wc * NI * 16 + j * 16 + lr;
        redS[slot * BN + c] = csum[j];
        redQ[slot * BN + c] = csq[j];
    }
    __syncthreads();
    if (tid < BN) {
        float s = 0.f, qq = 0.f;
        for (int sl = 0; sl < WM * 4; ++sl) { s += redS[sl * BN + tid]; qq += redQ[sl * BN + tid]; }
        partials[((size_t)mblk * 2 + 0) * O_DIM + bn0 + tid] = s;
        partials[((size_t)mblk * 2 + 1) * O_DIM + bn0 + tid] = qq;
    }
}

__global__ void bn_finalize(const float* __restrict__ partials,
                            const float* __restrict__ gamma,
                            const float* __restrict__ beta,
                            float* __restrict__ scsh, int nmblk)
{
    int o = threadIdx.x;   // 512 threads
    float s = 0.f, q = 0.f;
    for (int mb = 0; mb < nmblk; ++mb) {
        s += partials[((size_t)mb*2 + 0)*O_DIM + o];
        q += partials[((size_t)mb*2 + 1)*O_DIM + o];
    }
    const float invn = 1.f / (float)TBN_DIM;
    float mean = s * invn;
    float var  = q * invn - mean*mean;
    float sc   = gamma[o] * rsqrtf(var + 1e-5f);
    scsh[o]        = sc;
    scsh[O_DIM+o]  = beta[o] - mean*sc;
}

__global__ void bn_apply(float* __restrict__ out, const float* __restrict__ scsh)
{
    const size_t total4 = (size_t)TBN_DIM * O_DIM / 4;
    const float4* sc4 = (const float4*)scsh;
    const float4* sh4 = (const float4*)(scsh + O_DIM);
    size_t stride = (size_t)gridDim.x * blockDim.x;
    for (size_t idx = (size_t)blockIdx.x*blockDim.x + threadIdx.x; idx < total4; idx += stride) {
        float4 v = ((float4*)out)[idx];
        int c4 = (int)(idx & (O_DIM/4 - 1));
        float4 sc = sc4[c4], sh = sh4[c4];
        v.x = v.x*sc.x + sh.x;
        v.y = v.y*sc.y + sh.y;
        v.z = v.z*sc.z + sh.z;
        v.w = v.w*sc.w + sh.w;
        ((float4*)out)[idx] = v;
    }
}

extern "C" void kernel_launch(void* const* d_in, const int* in_sizes, int n_in,
                              void* d_out, int out_size, void* d_ws, size_t ws_size,
                              hipStream_t stream) {
    const float* x     = (const float*)d_in[0];
    const float* W1    = (const float*)d_in[1];
    const float* b1    = (const float*)d_in[2];
    const float* Wrec  = (const float*)d_in[3];
    const float* brec  = (const float*)d_in[4];
    const float* wlif  = (const float*)d_in[5];
    const float* W2    = (const float*)d_in[6];
    const float* b2    = (const float*)d_in[7];
    const float* gamma = (const float*)d_in[8];
    const float* beta  = (const float*)d_in[9];
    float* out = (float*)d_out;

    // ws layout (~415.8 MB, within round-1's proven 417.3 MB footprint)
    char* w = (char*)d_ws;
    float*          curr   = (float*)w;                            // 256 MB
    unsigned short* spk    = (unsigned short*)(w + 268435456);     // 128 MB
    float*          vstate = (float*)(w + 402653184);              // 8 MB
    float*          wrecT  = (float*)(w + 411041792);              // 4 MB (scan only)
    unsigned long long* mring = (unsigned long long*)(w + 415236096); // 2 x 256 KB
    unsigned short* w2p    = (unsigned short*)(w + 411041792);     // overlays wrecT after scan
    float* partials = curr;                 // overlay: curr dead after scan
    float* scsh     = curr + 512 * 2 * O_DIM;

    const int W2N = O_DIM * H_DIM;          // 524288
    const size_t MWORDS = (size_t)BNROWS * 16;   // 32768 words per slot

    // fc1: curr = x @ W1^T + b1   (proven frozen-chain fp32 engine)
    gemm_fc1<128,128,16,8,8>
        <<<dim3(H_DIM/128, TBN_DIM/128), 256, 0, stream>>>(
            x, W1, C_DIM, H_DIM, b1, curr);

    // one-time Wrec transpose (needed by the scan)
    wrec_transpose<<<dim3(32, 32), 256, 0, stream>>>(Wrec, wrecT);

    // t=0 elementwise (bit-exact), emits mask words into ring slot 0
    step0_kernel<<<dim3(2048), 256, 0, stream>>>(curr, brec, wlif, vstate, spk,
                                                 mring);

    // recurrent scan t=1..31: mask-fed sparse gather, b128 branchless quads
    for (int t = 1; t < T_STEPS; ++t) {
        const unsigned long long* mprev = mring + ((t - 1) & 1) * MWORDS;
        unsigned long long*       mout  = mring + (t & 1) * MWORDS;
        rec_sparse<<<dim3(H_DIM/256, BNROWS/32), 256, 0, stream>>>(
            mprev, wrecT, brec,
            curr + (size_t)t * BNROWS * H_DIM, wlif, vstate,
            spk + (size_t)t * BNROWS * H_DIM, mout);
    }

    // fc2 (BN-only consumer): 2-plane bf16 MFMA + fused BN partials
    split3_w<<<dim3(256), 256, 0, stream>>>(W2, w2p, w2p + W2N, w2p + 2 * W2N, W2N / 4);
    mfma_fc2<128, 128, 2, 2, 4, 4>
        <<<dim3(O_DIM/128, TBN_DIM/128), 256, 0, stream>>>(
            spk, w2p, w2p + W2N, H_DIM, b2, out, O_DIM, partials);

    bn_finalize<<<1, O_DIM, 0, stream>>>(partials, gamma, beta, scsh, TBN_DIM/128);
    bn_apply<<<2048, 256, 0, stream>>>(out, scsh);
}

// Round 11
// 2764.572 us; speedup vs baseline: 1.4769x; 1.0328x over previous
//
#include <hip/hip_runtime.h>
#include <cstdint>
#include <cstddef>

#define T_STEPS 32
#define BNROWS  2048     // B*N
#define C_DIM   512
#define H_DIM   1024
#define O_DIM   512
#define TBN_DIM 65536    // T_STEPS*BNROWS

typedef __attribute__((ext_vector_type(8))) short bf16x8;
typedef __attribute__((ext_vector_type(4))) float f32x4;

__device__ __forceinline__ float bf2f(unsigned short u){
    return __uint_as_float(((unsigned int)u) << 16);
}

// Exact 3-way truncation split: x == h + m + l exactly.
__device__ __forceinline__ void split3(float x, unsigned short& h,
                                       unsigned short& m, unsigned short& l){
    unsigned u = __float_as_uint(x);
    h = (unsigned short)(u >> 16);
    float r1 = x - __uint_as_float(u & 0xFFFF0000u);
    unsigned u1 = __float_as_uint(r1);
    m = (unsigned short)(u1 >> 16);
    float r2 = r1 - __uint_as_float(u1 & 0xFFFF0000u);
    l = (unsigned short)(__float_as_uint(r2) >> 16);
}

__global__ void split3_w(const float* __restrict__ src,
                         unsigned short* __restrict__ hi,
                         unsigned short* __restrict__ mi,
                         unsigned short* __restrict__ lo, int n4)
{
    int i = blockIdx.x * blockDim.x + threadIdx.x;
    int stride = gridDim.x * blockDim.x;
    for (; i < n4; i += stride) {
        float4 v = ((const float4*)src)[i];
        ushort4 h, m, l;
        split3(v.x, h.x, m.x, l.x); split3(v.y, h.y, m.y, l.y);
        split3(v.z, h.z, m.z, l.z); split3(v.w, h.w, m.w, l.w);
        ((ushort4*)hi)[i] = h;
        ((ushort4*)mi)[i] = m;
        ((ushort4*)lo)[i] = l;
    }
}

// 8-byte-granular LDS helpers for the MFMA kernel (LP=40 ushort rows = 80 B)
__device__ __forceinline__ void st8x2(unsigned short* p, int4 v){
    ((int2*)p)[0] = make_int2(v.x, v.y);
    ((int2*)p)[1] = make_int2(v.z, v.w);
}
__device__ __forceinline__ bf16x8 ld_frag(const unsigned short* p){
    union { bf16x8 v; ushort4 u[2]; } t;
    t.u[0] = *(const ushort4*)(p);
    t.u[1] = *(const ushort4*)(p + 4);
    return t.v;
}

// WrecT[k][n] = Wrec[n][k]  (one-time 4 MB transpose)
__global__ void wrec_transpose(const float* __restrict__ src,
                               float* __restrict__ dst)
{
    __shared__ float tile[32][33];
    const int bx = blockIdx.x * 32, by = blockIdx.y * 32;
    const int tx = threadIdx.x & 31, ty = threadIdx.x >> 5;   // 32x8
#pragma unroll
    for (int r = 0; r < 32; r += 8)
        tile[ty + r][tx] = src[(size_t)(by + ty + r) * H_DIM + bx + tx];
    __syncthreads();
#pragma unroll
    for (int r = 0; r < 32; r += 8)
        dst[(size_t)(bx + ty + r) * H_DIM + by + tx] = tile[tx][ty + r];
}

// t=0 PLIF step (prev spikes all zero). v math bit-identical to round-5..10.
__global__ __launch_bounds__(256)
void step0_kernel(const float* __restrict__ curr0,
                  const float* __restrict__ brec,
                  const float* __restrict__ wlif,
                  float* __restrict__ vstate,
                  unsigned short* __restrict__ spk0,
                  unsigned long long* __restrict__ masks0)
{
    const float decay = 1.f / (1.f + expf(-wlif[0]));
    const int lane = threadIdx.x & 63;
    const int wid  = threadIdx.x >> 6;
    const int wtotal = gridDim.x * 4;
    const int NT = BNROWS * (H_DIM / 64);   // 32768 wave-tasks
    for (int task = blockIdx.x * 4 + wid; task < NT; task += wtotal) {
        int row = task >> 4, w = task & 15;
        int col = w * 64 + lane;
        size_t idx = (size_t)row * H_DIM + col;
        float c = curr0[idx];
        float v = __fmul_rn(__fadd_rn(brec[col], c), decay);
        bool s = (v - 1.0f) >= 0.0f;
        vstate[idx] = s ? 0.f : v;
        spk0[idx]   = s ? (unsigned short)0x3F80 : (unsigned short)0;
        unsigned long long bm = __ballot(s);
        if (lane == 0) masks0[task] = bm;
    }
}

// ======== fc1: fp32 VALU GEMM, single-buffered (round-7..10 proven). ========
template<int BM, int BN, int BK, int TM, int TN>
__global__ __launch_bounds__(256)
void gemm_fc1(const float* __restrict__ Ap,
              const float* __restrict__ Bp,
              int K, int ldc,
              const float* __restrict__ bias,
              float* __restrict__ Cout)
{
    constexpr int BMP = BM + 4;
    constexpr int BNP = BN + 4;
    __shared__ float smem[BK*BMP + BK*BNP];
    float* As = smem;
    float* Bs = smem + BK*BMP;

    const int tid = threadIdx.x;
    constexpr int TXN = BN / TN;
    const int tx = tid % TXN;
    const int ty = tid / TXN;
    const int bm0 = blockIdx.y * BM;
    const int bn0 = blockIdx.x * BN;

    constexpr int CPR = BK / 4;

    float acc[TM][TN];
#pragma unroll
    for (int i = 0; i < TM; ++i)
#pragma unroll
        for (int j = 0; j < TN; ++j) acc[i][j] = 0.f;

    for (int kt = 0; kt < K; kt += BK) {
        {
            constexpr int PT = (BM*BK/4)/256;
#pragma unroll
            for (int it = 0; it < PT; ++it) {
                int e   = it*256 + tid;
                int row = e / CPR;
                int c4  = e % CPR;
                float4 fv = *(const float4*)(Ap + (size_t)(bm0+row)*K + kt + c4*4);
                As[(c4*4+0)*BMP + row] = fv.x;
                As[(c4*4+1)*BMP + row] = fv.y;
                As[(c4*4+2)*BMP + row] = fv.z;
                As[(c4*4+3)*BMP + row] = fv.w;
            }
        }
        {
            constexpr int PT = (BN*BK/4)/256;
#pragma unroll
            for (int it = 0; it < PT; ++it) {
                int e   = it*256 + tid;
                int row = e / CPR;
                int c4  = e % CPR;
                float4 fv = *(const float4*)(Bp + (size_t)(bn0+row)*K + kt + c4*4);
                Bs[(c4*4+0)*BNP + row] = fv.x;
                Bs[(c4*4+1)*BNP + row] = fv.y;
                Bs[(c4*4+2)*BNP + row] = fv.z;
                Bs[(c4*4+3)*BNP + row] = fv.w;
            }
        }
        __syncthreads();
#pragma unroll
        for (int k = 0; k < BK; ++k) {
            float a[TM], b[TN];
            float4 t0 = *(const float4*)&As[k*BMP + ty*8];
            float4 t1 = *(const float4*)&As[k*BMP + ty*8 + 4];
            a[0]=t0.x; a[1]=t0.y; a[2]=t0.z; a[3]=t0.w;
            a[4]=t1.x; a[5]=t1.y; a[6]=t1.z; a[7]=t1.w;
            float4 u0 = *(const float4*)&Bs[k*BNP + tx*4];
            float4 u1 = *(const float4*)&Bs[k*BNP + 64 + tx*4];
            b[0]=u0.x; b[1]=u0.y; b[2]=u0.z; b[3]=u0.w;
            b[4]=u1.x; b[5]=u1.y; b[6]=u1.z; b[7]=u1.w;
#pragma unroll
            for (int i = 0; i < TM; ++i)
#pragma unroll
                for (int j = 0; j < TN; ++j)
                    acc[i][j] = fmaf(a[i], b[j], acc[i][j]);
        }
        __syncthreads();
    }

#pragma unroll
    for (int i = 0; i < TM; ++i) {
        int m = bm0 + ty*TM + i;
        int n0 = bn0 + tx*4;
        int n1 = bn0 + 64 + tx*4;
        float4 bv0 = *(const float4*)&bias[n0];
        float4 bv1 = *(const float4*)&bias[n1];
        float4 o0, o1;
        o0.x = acc[i][0] + bv0.x; o0.y = acc[i][1] + bv0.y;
        o0.z = acc[i][2] + bv0.z; o0.w = acc[i][3] + bv0.w;
        o1.x = acc[i][4] + bv1.x; o1.y = acc[i][5] + bv1.y;
        o1.z = acc[i][6] + bv1.z; o1.w = acc[i][7] + bv1.w;
        *(float4*)&Cout[(size_t)m*ldc + n0] = o0;
        *(float4*)&Cout[(size_t)m*ldc + n1] = o1;
    }
}

// spread2: 32 bits -> every 2nd bit of a 64-bit word
__device__ __forceinline__ unsigned long long spread2(unsigned long long x){
    x &= 0xFFFFFFFFull;
    x = (x | (x << 16)) & 0x0000FFFF0000FFFFull;
    x = (x | (x << 8 )) & 0x00FF00FF00FF00FFull;
    x = (x | (x << 4 )) & 0x0F0F0F0F0F0F0F0Full;
    x = (x | (x << 2 )) & 0x3333333333333333ull;
    x = (x | (x << 1 )) & 0x5555555555555555ull;
    return x;
}

// ======== rec step v3: same branchless-quad sparse gather as round 10, but
// BN=128 / 2 cols per lane / 512-block grid -> 2 blocks/CU, 2 waves/SIMD.
// Chain bit-identical: ascending-k quads, fmaf(w,1,acc)==acc+w,
// fmaf(w,0,acc)==acc (acc never -0). Uniform trip counts, no divergence.
__global__ __launch_bounds__(256)
void rec_sparse(const unsigned long long* __restrict__ masks_prev, // [2048][16]
                const float* __restrict__ WrecT,    // [k][n] transposed
                const float* __restrict__ brec,
                const float* __restrict__ curr_t,
                const float* __restrict__ wlif,
                float* __restrict__ vstate,
                unsigned short* __restrict__ spk_out,
                unsigned long long* __restrict__ masks_out)
{
    constexpr int BM = 32, BN = 128, BK = 64, BNP = 132;
    __shared__ float Bs[BK * BNP];                      // 33.8 KB
    __shared__ unsigned long long msk[BM * 16];         // 4 KB

    const int tid  = threadIdx.x;
    const int lane = tid & 63;
    const int wid  = tid >> 6;          // 4 waves
    const int bn0  = blockIdx.x * BN;   // 8 n-blocks
    const int bm0  = blockIdx.y * BM;   // 64 m-blocks
    const int r0   = wid * 8;           // 8 rows per wave
    const unsigned long long MSB = 0x8000000000000000ull;

    // preload this block's 32x16 mask words (4 KB, one int4 per thread)
    ((int4*)msk)[tid] = ((const int4*)(masks_prev + (size_t)bm0 * 16))[tid];

    float acc[8][2];
#pragma unroll
    for (int i = 0; i < 8; ++i) { acc[i][0] = 0.f; acc[i][1] = 0.f; }

    for (int kt = 0; kt < H_DIM; kt += BK) {
        // stage Bs[k][n] = WrecT[kt+k][bn0+n]  (contiguous float4 both sides)
#pragma unroll
        for (int it = 0; it < 8; ++it) {
            int e  = it * 256 + tid;        // 0..2047
            int k  = e >> 5;
            int n4 = e & 31;
            float4 fv = *(const float4*)(WrecT + (size_t)(kt + k) * H_DIM + bn0 + n4 * 4);
            *(float4*)&Bs[k * BNP + n4 * 4] = fv;
        }
        __syncthreads();
        const int wslot = kt >> 6;
#pragma unroll
        for (int i = 0; i < 8; ++i) {
            unsigned long long mv = msk[(r0 + i) * 16 + wslot];
            unsigned lo = __builtin_amdgcn_readfirstlane((unsigned)mv);
            unsigned hi = __builtin_amdgcn_readfirstlane((unsigned)(mv >> 32));
            unsigned long long m = ((unsigned long long)hi << 32) | lo;
            int pc = __popcll(m);
            float a0 = acc[i][0], a1 = acc[i][1];
            for (int s = 0; s < pc; s += 4) {
                int k0 = __builtin_ctzll(m | MSB); m &= m - 1;
                int k1 = __builtin_ctzll(m | MSB); m &= m - 1;
                int k2 = __builtin_ctzll(m | MSB); m &= m - 1;
                int k3 = __builtin_ctzll(m | MSB); m &= m - 1;
                float2 w0 = *(const float2*)&Bs[k0 * BNP + lane * 2];
                float2 w1 = *(const float2*)&Bs[k1 * BNP + lane * 2];
                float2 w2 = *(const float2*)&Bs[k2 * BNP + lane * 2];
                float2 w3 = *(const float2*)&Bs[k3 * BNP + lane * 2];
                float s1v = (s + 1 < pc) ? 1.f : 0.f;
                float s2v = (s + 2 < pc) ? 1.f : 0.f;
                float s3v = (s + 3 < pc) ? 1.f : 0.f;
                a0 += w0.x;               a1 += w0.y;
                a0 = fmaf(w1.x, s1v, a0); a1 = fmaf(w1.y, s1v, a1);
                a0 = fmaf(w2.x, s2v, a0); a1 = fmaf(w2.y, s2v, a1);
                a0 = fmaf(w3.x, s3v, a0); a1 = fmaf(w3.y, s3v, a1);
            }
            acc[i][0] = a0; acc[i][1] = a1;
        }
        __syncthreads();
    }

    // epilogue: PLIF update for 2 cols per lane, verbatim expressions
    const float decay = 1.f / (1.f + expf(-wlif[0]));
    const int n0 = bn0 + lane * 2;
    float2 bv = *(const float2*)&brec[n0];
#pragma unroll
    for (int i = 0; i < 8; ++i) {
        int mrow = bm0 + r0 + i;
        size_t idx = (size_t)mrow * H_DIM + n0;
        float2 cv = *(const float2*)&curr_t[idx];
        float2 vv = *(const float2*)&vstate[idx];
        float inp0 = acc[i][0] + bv.x + cv.x;
        float inp1 = acc[i][1] + bv.y + cv.y;
        float v0 = vv.x + (inp0 - vv.x) * decay;
        float v1 = vv.y + (inp1 - vv.y) * decay;
        bool s0 = (v0 - 1.0f) >= 0.0f, s1 = (v1 - 1.0f) >= 0.0f;
        float2 vo; vo.x = s0 ? 0.f : v0; vo.y = s1 ? 0.f : v1;
        ushort2 sp;
        sp.x = s0 ? (unsigned short)0x3F80 : (unsigned short)0;
        sp.y = s1 ? (unsigned short)0x3F80 : (unsigned short)0;
        *(float2*)&vstate[idx]   = vo;
        *(ushort2*)&spk_out[idx] = sp;
        // masks: word w of this block covers cols bn0+64w; bit (2*l+j mod 64)
        unsigned long long b0 = __ballot(s0);
        unsigned long long b1 = __ballot(s1);
        if (lane == 0) {
            unsigned long long w0 =  spread2(b0)        | (spread2(b1) << 1);
            unsigned long long w1 =  spread2(b0 >> 32)  | (spread2(b1 >> 32) << 1);
            masks_out[(size_t)mrow * 16 + blockIdx.x * 2 + 0] = w0;
            masks_out[(size_t)mrow * 16 + blockIdx.x * 2 + 1] = w1;
        }
    }
}

// ======== MFMA GEMM for fc2 only (feeds BN; loose tolerance) ========
template<int BM, int BN, int WM, int WN, int MI, int NI>
__global__ __launch_bounds__(256)
void mfma_fc2(const unsigned short* __restrict__ Aptr,
              const unsigned short* __restrict__ Bhi,
              const unsigned short* __restrict__ Bmi,
              int K,
              const float* __restrict__ bias,
              float* __restrict__ Cout, int ldc,
              float* __restrict__ partials)
{
    constexpr int LP  = 40;
    constexpr int APL = BM * LP;
    constexpr int BPL = BN * LP;
    __shared__ alignas(16) unsigned short sA[APL];
    __shared__ alignas(16) unsigned short sB[2 * BPL];

    const int nwg = gridDim.x * gridDim.y;
    const int f   = blockIdx.y * gridDim.x + blockIdx.x;
    const int q   = nwg >> 3;
    const int lg  = (f & 7) * q + (f >> 3);
    const int bn0  = (lg % gridDim.x) * BN;
    const int mblk = lg / gridDim.x;
    const int bm0  = mblk * BM;

    const int tid  = threadIdx.x;
    const int lane = tid & 63;
    const int wid  = tid >> 6;
    const int wr   = wid / WN;
    const int wc   = wid % WN;
    const int lr   = lane & 15;
    const int lk   = lane >> 4;

    f32x4 accB[MI][NI], accS[MI][NI];
#pragma unroll
    for (int i = 0; i < MI; ++i)
#pragma unroll
        for (int j = 0; j < NI; ++j) {
            accB[i][j] = (f32x4){0.f, 0.f, 0.f, 0.f};
            accS[i][j] = (f32x4){0.f, 0.f, 0.f, 0.f};
        }

    for (int kt = 0; kt < K; kt += 32) {
#pragma unroll
        for (int p = 0; p < BM / 64; ++p) {
            int e = p * 256 + tid;
            int row = e >> 2, c8 = e & 3;
            int4 v = *(const int4*)(Aptr + (size_t)(bm0 + row) * K + kt + c8 * 8);
            st8x2(&sA[row * LP + c8 * 8], v);
        }
#pragma unroll
        for (int p = 0; p < BN / 64; ++p) {
            int e = p * 256 + tid;
            int row = e >> 2, c8 = e & 3;
            size_t g = (size_t)(bn0 + row) * K + kt + c8 * 8;
            st8x2(&sB[row * LP + c8 * 8],       *(const int4*)(Bhi + g));
            st8x2(&sB[BPL + row * LP + c8 * 8], *(const int4*)(Bmi + g));
        }
        __syncthreads();

        bf16x8 af[MI], b0[NI], b1[NI];
#pragma unroll
        for (int i = 0; i < MI; ++i) {
            int r = wr * MI * 16 + i * 16 + lr;
            af[i] = ld_frag(&sA[r * LP + lk * 8]);
        }
#pragma unroll
        for (int j = 0; j < NI; ++j) {
            int r = wc * NI * 16 + j * 16 + lr;
            b0[j] = ld_frag(&sB[r * LP + lk * 8]);
            b1[j] = ld_frag(&sB[BPL + r * LP + lk * 8]);
        }
#pragma unroll
        for (int i = 0; i < MI; ++i)
#pragma unroll
            for (int j = 0; j < NI; ++j) {
                accB[i][j] = __builtin_amdgcn_mfma_f32_16x16x32_bf16(af[i], b0[j], accB[i][j], 0, 0, 0);
                accS[i][j] = __builtin_amdgcn_mfma_f32_16x16x32_bf16(af[i], b1[j], accS[i][j], 0, 0, 0);
            }
        __syncthreads();
    }

    float csum[NI], csq[NI];
#pragma unroll
    for (int j = 0; j < NI; ++j) { csum[j] = 0.f; csq[j] = 0.f; }
#pragma unroll
    for (int i = 0; i < MI; ++i)
#pragma unroll
        for (int j = 0; j < NI; ++j) {
            int col = bn0 + wc * NI * 16 + j * 16 + lr;
            float bv = bias[col];
#pragma unroll
            for (int r = 0; r < 4; ++r) {
                int row = bm0 + wr * MI * 16 + i * 16 + lk * 4 + r;
                float o = (accB[i][j][r] + accS[i][j][r]) + bv;
                Cout[(size_t)row * ldc + col] = o;
                csum[j] += o;
                csq[j]  += o * o;
            }
        }
    __syncthreads();
    float* redS = (float*)sA;
    float* redQ = (float*)sB;
    const int slot = wr * 4 + lk;
#pragma unroll
    for (int j = 0; j < NI; ++j) {
        int c = wc * NI * 16 + j * 16 + lr;
        redS[slot * BN + c] = csum[j];
        redQ[slot * BN + c] = csq[j];
    }
    __syncthreads();
    if (tid < BN) {
        float s = 0.f, qq = 0.f;
        for (int sl = 0; sl < WM * 4; ++sl) { s += redS[sl * BN + tid]; qq += redQ[sl * BN + tid]; }
        partials[((size_t)mblk * 2 + 0) * O_DIM + bn0 + tid] = s;
        partials[((size_t)mblk * 2 + 1) * O_DIM + bn0 + tid] = qq;
    }
}

__global__ void bn_finalize(const float* __restrict__ partials,
                            const float* __restrict__ gamma,
                            const float* __restrict__ beta,
                            float* __restrict__ scsh, int nmblk)
{
    int o = threadIdx.x;   // 512 threads
    float s = 0.f, q = 0.f;
    for (int mb = 0; mb < nmblk; ++mb) {
        s += partials[((size_t)mb*2 + 0)*O_DIM + o];
        q += partials[((size_t)mb*2 + 1)*O_DIM + o];
    }
    const float invn = 1.f / (float)TBN_DIM;
    float mean = s * invn;
    float var  = q * invn - mean*mean;
    float sc   = gamma[o] * rsqrtf(var + 1e-5f);
    scsh[o]        = sc;
    scsh[O_DIM+o]  = beta[o] - mean*sc;
}

__global__ void bn_apply(float* __restrict__ out, const float* __restrict__ scsh)
{
    const size_t total4 = (size_t)TBN_DIM * O_DIM / 4;
    const float4* sc4 = (const float4*)scsh;
    const float4* sh4 = (const float4*)(scsh + O_DIM);
    size_t stride = (size_t)gridDim.x * blockDim.x;
    for (size_t idx = (size_t)blockIdx.x*blockDim.x + threadIdx.x; idx < total4; idx += stride) {
        float4 v = ((float4*)out)[idx];
        int c4 = (int)(idx & (O_DIM/4 - 1));
        float4 sc = sc4[c4], sh = sh4[c4];
        v.x = v.x*sc.x + sh.x;
        v.y = v.y*sc.y + sh.y;
        v.z = v.z*sc.z + sh.z;
        v.w = v.w*sc.w + sh.w;
        ((float4*)out)[idx] = v;
    }
}

extern "C" void kernel_launch(void* const* d_in, const int* in_sizes, int n_in,
                              void* d_out, int out_size, void* d_ws, size_t ws_size,
                              hipStream_t stream) {
    const float* x     = (const float*)d_in[0];
    const float* W1    = (const float*)d_in[1];
    const float* b1    = (const float*)d_in[2];
    const float* Wrec  = (const float*)d_in[3];
    const float* brec  = (const float*)d_in[4];
    const float* wlif  = (const float*)d_in[5];
    const float* W2    = (const float*)d_in[6];
    const float* b2    = (const float*)d_in[7];
    const float* gamma = (const float*)d_in[8];
    const float* beta  = (const float*)d_in[9];
    float* out = (float*)d_out;

    // ws layout (~415.8 MB, within round-1's proven 417.3 MB footprint)
    char* w = (char*)d_ws;
    float*          curr   = (float*)w;                            // 256 MB
    unsigned short* spk    = (unsigned short*)(w + 268435456);     // 128 MB
    float*          vstate = (float*)(w + 402653184);              // 8 MB
    float*          wrecT  = (float*)(w + 411041792);              // 4 MB (scan only)
    unsigned long long* mring = (unsigned long long*)(w + 415236096); // 2 x 256 KB
    unsigned short* w2p    = (unsigned short*)(w + 411041792);     // overlays wrecT after scan
    float* partials = curr;                 // overlay: curr dead after scan
    float* scsh     = curr + 512 * 2 * O_DIM;

    const int W2N = O_DIM * H_DIM;          // 524288
    const size_t MWORDS = (size_t)BNROWS * 16;   // 32768 words per slot

    // fc1: curr = x @ W1^T + b1   (proven frozen-chain fp32 engine)
    gemm_fc1<128,128,16,8,8>
        <<<dim3(H_DIM/128, TBN_DIM/128), 256, 0, stream>>>(
            x, W1, C_DIM, H_DIM, b1, curr);

    // one-time Wrec transpose (needed by the scan)
    wrec_transpose<<<dim3(32, 32), 256, 0, stream>>>(Wrec, wrecT);

    // t=0 elementwise (bit-exact), emits mask words into ring slot 0
    step0_kernel<<<dim3(2048), 256, 0, stream>>>(curr, brec, wlif, vstate, spk,
                                                 mring);

    // recurrent scan t=1..31: mask-fed sparse gather, 2 blocks/CU occupancy
    for (int t = 1; t < T_STEPS; ++t) {
        const unsigned long long* mprev = mring + ((t - 1) & 1) * MWORDS;
        unsigned long long*       mout  = mring + (t & 1) * MWORDS;
        rec_sparse<<<dim3(H_DIM/128, BNROWS/32), 256, 0, stream>>>(
            mprev, wrecT, brec,
            curr + (size_t)t * BNROWS * H_DIM, wlif, vstate,
            spk + (size_t)t * BNROWS * H_DIM, mout);
    }

    // fc2 (BN-only consumer): 2-plane bf16 MFMA + fused BN partials
    split3_w<<<dim3(256), 256, 0, stream>>>(W2, w2p, w2p + W2N, w2p + 2 * W2N, W2N / 4);
    mfma_fc2<128, 128, 2, 2, 4, 4>
        <<<dim3(O_DIM/128, TBN_DIM/128), 256, 0, stream>>>(
            spk, w2p, w2p + W2N, H_DIM, b2, out, O_DIM, partials);

    bn_finalize<<<1, O_DIM, 0, stream>>>(partials, gamma, beta, scsh, TBN_DIM/128);
    bn_apply<<<2048, 256, 0, stream>>>(out, scsh);
}

// Round 12
// 1983.856 us; speedup vs baseline: 2.0581x; 1.3935x over previous
//
#include <hip/hip_runtime.h>
#include <cstdint>
#include <cstddef>

#define T_STEPS 32
#define BNROWS  2048     // B*N
#define C_DIM   512
#define H_DIM   1024
#define O_DIM   512
#define TBN_DIM 65536    // T_STEPS*BNROWS

typedef __attribute__((ext_vector_type(8))) short bf16x8;
typedef __attribute__((ext_vector_type(4))) float f32x4;

// Exact 3-way truncation split: x == h + m + l exactly.
__device__ __forceinline__ void split3(float x, unsigned short& h,
                                       unsigned short& m, unsigned short& l){
    unsigned u = __float_as_uint(x);
    h = (unsigned short)(u >> 16);
    float r1 = x - __uint_as_float(u & 0xFFFF0000u);
    unsigned u1 = __float_as_uint(r1);
    m = (unsigned short)(u1 >> 16);
    float r2 = r1 - __uint_as_float(u1 & 0xFFFF0000u);
    l = (unsigned short)(__float_as_uint(r2) >> 16);
}

__global__ void split3_w(const float* __restrict__ src,
                         unsigned short* __restrict__ hi,
                         unsigned short* __restrict__ mi,
                         unsigned short* __restrict__ lo, int n4)
{
    int i = blockIdx.x * blockDim.x + threadIdx.x;
    int stride = gridDim.x * blockDim.x;
    for (; i < n4; i += stride) {
        float4 v = ((const float4*)src)[i];
        ushort4 h, m, l;
        split3(v.x, h.x, m.x, l.x); split3(v.y, h.y, m.y, l.y);
        split3(v.z, h.z, m.z, l.z); split3(v.w, h.w, m.w, l.w);
        ((ushort4*)hi)[i] = h;
        ((ushort4*)mi)[i] = m;
        ((ushort4*)lo)[i] = l;
    }
}

// 8-byte-granular LDS helpers for the MFMA kernel (LP=40 ushort rows = 80 B)
__device__ __forceinline__ void st8x2(unsigned short* p, int4 v){
    ((int2*)p)[0] = make_int2(v.x, v.y);
    ((int2*)p)[1] = make_int2(v.z, v.w);
}
__device__ __forceinline__ bf16x8 ld_frag(const unsigned short* p){
    union { bf16x8 v; ushort4 u[2]; } t;
    t.u[0] = *(const ushort4*)(p);
    t.u[1] = *(const ushort4*)(p + 4);
    return t.v;
}

// WrecT[k][n] = Wrec[n][k]  (one-time 4 MB transpose)
__global__ void wrec_transpose(const float* __restrict__ src,
                               float* __restrict__ dst)
{
    __shared__ float tile[32][33];
    const int bx = blockIdx.x * 32, by = blockIdx.y * 32;
    const int tx = threadIdx.x & 31, ty = threadIdx.x >> 5;   // 32x8
#pragma unroll
    for (int r = 0; r < 32; r += 8)
        tile[ty + r][tx] = src[(size_t)(by + ty + r) * H_DIM + bx + tx];
    __syncthreads();
#pragma unroll
    for (int r = 0; r < 32; r += 8)
        dst[(size_t)(bx + ty + r) * H_DIM + by + tx] = tile[tx][ty + r];
}

// ======== fc1: fp32 VALU GEMM, single-buffered (round-7..11 proven). ========
template<int BM, int BN, int BK, int TM, int TN>
__global__ __launch_bounds__(256)
void gemm_fc1(const float* __restrict__ Ap,
              const float* __restrict__ Bp,
              int K, int ldc,
              const float* __restrict__ bias,
              float* __restrict__ Cout)
{
    constexpr int BMP = BM + 4;
    constexpr int BNP = BN + 4;
    __shared__ float smem[BK*BMP + BK*BNP];
    float* As = smem;
    float* Bs = smem + BK*BMP;

    const int tid = threadIdx.x;
    constexpr int TXN = BN / TN;
    const int tx = tid % TXN;
    const int ty = tid / TXN;
    const int bm0 = blockIdx.y * BM;
    const int bn0 = blockIdx.x * BN;

    constexpr int CPR = BK / 4;

    float acc[TM][TN];
#pragma unroll
    for (int i = 0; i < TM; ++i)
#pragma unroll
        for (int j = 0; j < TN; ++j) acc[i][j] = 0.f;

    for (int kt = 0; kt < K; kt += BK) {
        {
            constexpr int PT = (BM*BK/4)/256;
#pragma unroll
            for (int it = 0; it < PT; ++it) {
                int e   = it*256 + tid;
                int row = e / CPR;
                int c4  = e % CPR;
                float4 fv = *(const float4*)(Ap + (size_t)(bm0+row)*K + kt + c4*4);
                As[(c4*4+0)*BMP + row] = fv.x;
                As[(c4*4+1)*BMP + row] = fv.y;
                As[(c4*4+2)*BMP + row] = fv.z;
                As[(c4*4+3)*BMP + row] = fv.w;
            }
        }
        {
            constexpr int PT = (BN*BK/4)/256;
#pragma unroll
            for (int it = 0; it < PT; ++it) {
                int e   = it*256 + tid;
                int row = e / CPR;
                int c4  = e % CPR;
                float4 fv = *(const float4*)(Bp + (size_t)(bn0+row)*K + kt + c4*4);
                Bs[(c4*4+0)*BNP + row] = fv.x;
                Bs[(c4*4+1)*BNP + row] = fv.y;
                Bs[(c4*4+2)*BNP + row] = fv.z;
                Bs[(c4*4+3)*BNP + row] = fv.w;
            }
        }
        __syncthreads();
#pragma unroll
        for (int k = 0; k < BK; ++k) {
            float a[TM], b[TN];
            float4 t0 = *(const float4*)&As[k*BMP + ty*8];
            float4 t1 = *(const float4*)&As[k*BMP + ty*8 + 4];
            a[0]=t0.x; a[1]=t0.y; a[2]=t0.z; a[3]=t0.w;
            a[4]=t1.x; a[5]=t1.y; a[6]=t1.z; a[7]=t1.w;
            float4 u0 = *(const float4*)&Bs[k*BNP + tx*4];
            float4 u1 = *(const float4*)&Bs[k*BNP + 64 + tx*4];
            b[0]=u0.x; b[1]=u0.y; b[2]=u0.z; b[3]=u0.w;
            b[4]=u1.x; b[5]=u1.y; b[6]=u1.z; b[7]=u1.w;
#pragma unroll
            for (int i = 0; i < TM; ++i)
#pragma unroll
                for (int j = 0; j < TN; ++j)
                    acc[i][j] = fmaf(a[i], b[j], acc[i][j]);
        }
        __syncthreads();
    }

#pragma unroll
    for (int i = 0; i < TM; ++i) {
        int m = bm0 + ty*TM + i;
        int n0 = bn0 + tx*4;
        int n1 = bn0 + 64 + tx*4;
        float4 bv0 = *(const float4*)&bias[n0];
        float4 bv1 = *(const float4*)&bias[n1];
        float4 o0, o1;
        o0.x = acc[i][0] + bv0.x; o0.y = acc[i][1] + bv0.y;
        o0.z = acc[i][2] + bv0.z; o0.w = acc[i][3] + bv0.w;
        o1.x = acc[i][4] + bv1.x; o1.y = acc[i][5] + bv1.y;
        o1.z = acc[i][6] + bv1.z; o1.w = acc[i][7] + bv1.w;
        *(float4*)&Cout[(size_t)m*ldc + n0] = o0;
        *(float4*)&Cout[(size_t)m*ldc + n1] = o1;
    }
}

// Morton spread: 16 bits -> every 4th bit of a 64-bit word (round-10 verified)
__device__ __forceinline__ unsigned long long spread4(unsigned long long x){
    x &= 0xFFFFull;
    x = (x | (x << 24)) & 0x000000FF000000FFull;
    x = (x | (x << 12)) & 0x000F000F000F000Full;
    x = (x | (x << 6 )) & 0x0303030303030303ull;
    x = (x | (x << 3 )) & 0x1111111111111111ull;
    return x;
}

// ======== mega_scan: ALL 32 timesteps in one kernel. One wave per row;
// v + spike masks live in registers; no LDS, no barriers, no launches.
// Gather: per spiking k (ascending words, ascending bits — identical add
// sequence to rounds 8-11's passing chain), read WrecT[k] from L2 with 4
// coalesced dwordx4; branchless selector-fmaf quads (round-10 proven:
// fmaf(w,1,acc)==acc+w, fmaf(w,0,acc)==acc, acc never -0).
// t=0 folds in exactly: masks=0 -> no gather; (0+b)+c==b+c, 0+(inp-0)*d==
// inp*d bitwise. Col ownership: col = 256*q + 4*lane + j (q,j in 0..3).
// Mask words rebuilt via the round-10-verified spread4 ballot formula.
__global__ __launch_bounds__(256)
void mega_scan(const float* __restrict__ curr,
               const float* __restrict__ WrecT,   // [k][n]
               const float* __restrict__ brec,
               const float* __restrict__ wlif,
               unsigned short* __restrict__ spk)
{
    const int lane = threadIdx.x & 63;
    const int wid  = threadIdx.x >> 6;
    const int row  = blockIdx.x * 4 + wid;
    const float decay = 1.f / (1.f + expf(-wlif[0]));
    const unsigned long long MSB = 0x8000000000000000ull;

    float v[4][4];
#pragma unroll
    for (int q = 0; q < 4; ++q)
#pragma unroll
        for (int j = 0; j < 4; ++j) v[q][j] = 0.f;

    float brv[4][4];
#pragma unroll
    for (int q = 0; q < 4; ++q) {
        float4 bv = *(const float4*)&brec[q * 256 + lane * 4];
        brv[q][0] = bv.x; brv[q][1] = bv.y; brv[q][2] = bv.z; brv[q][3] = bv.w;
    }

    unsigned long long mask[16];
#pragma unroll
    for (int w = 0; w < 16; ++w) mask[w] = 0ull;

    for (int t = 0; t < T_STEPS; ++t) {
        float acc[4][4];
#pragma unroll
        for (int q = 0; q < 4; ++q)
#pragma unroll
            for (int j = 0; j < 4; ++j) acc[q][j] = 0.f;

        // ---- sparse gather: words ascending, bits ascending ----
#pragma unroll
        for (int w = 0; w < 16; ++w) {
            unsigned long long m = mask[w];
            int pc = __popcll(m);
            for (int s = 0; s < pc; s += 4) {
                int k0 = __builtin_ctzll(m | MSB); m &= m - 1;
                int k1 = __builtin_ctzll(m | MSB); m &= m - 1;
                int k2 = __builtin_ctzll(m | MSB); m &= m - 1;
                int k3 = __builtin_ctzll(m | MSB); m &= m - 1;
                const float* r0 = WrecT + ((size_t)(w * 64 + k0) << 10) + lane * 4;
                const float* r1 = WrecT + ((size_t)(w * 64 + k1) << 10) + lane * 4;
                const float* r2 = WrecT + ((size_t)(w * 64 + k2) << 10) + lane * 4;
                const float* r3 = WrecT + ((size_t)(w * 64 + k3) << 10) + lane * 4;
                float4 w0[4], w1[4], w2[4], w3[4];
#pragma unroll
                for (int q = 0; q < 4; ++q) {
                    w0[q] = *(const float4*)(r0 + q * 256);
                    w1[q] = *(const float4*)(r1 + q * 256);
                    w2[q] = *(const float4*)(r2 + q * 256);
                    w3[q] = *(const float4*)(r3 + q * 256);
                }
                float s1v = (s + 1 < pc) ? 1.f : 0.f;
                float s2v = (s + 2 < pc) ? 1.f : 0.f;
                float s3v = (s + 3 < pc) ? 1.f : 0.f;
#pragma unroll
                for (int q = 0; q < 4; ++q) {
                    acc[q][0] += w0[q].x;
                    acc[q][0] = fmaf(w1[q].x, s1v, acc[q][0]);
                    acc[q][0] = fmaf(w2[q].x, s2v, acc[q][0]);
                    acc[q][0] = fmaf(w3[q].x, s3v, acc[q][0]);
                    acc[q][1] += w0[q].y;
                    acc[q][1] = fmaf(w1[q].y, s1v, acc[q][1]);
                    acc[q][1] = fmaf(w2[q].y, s2v, acc[q][1]);
                    acc[q][1] = fmaf(w3[q].y, s3v, acc[q][1]);
                    acc[q][2] += w0[q].z;
                    acc[q][2] = fmaf(w1[q].z, s1v, acc[q][2]);
                    acc[q][2] = fmaf(w2[q].z, s2v, acc[q][2]);
                    acc[q][2] = fmaf(w3[q].z, s3v, acc[q][2]);
                    acc[q][3] += w0[q].w;
                    acc[q][3] = fmaf(w1[q].w, s1v, acc[q][3]);
                    acc[q][3] = fmaf(w2[q].w, s2v, acc[q][3]);
                    acc[q][3] = fmaf(w3[q].w, s3v, acc[q][3]);
                }
            }
        }

        // ---- PLIF update + spikes + ballots (verbatim expressions) ----
        const float* cr = curr + (((size_t)t * BNROWS + row) << 10);
        unsigned short* sr = spk + (((size_t)t * BNROWS + row) << 10);
        unsigned long long bal[4][4];
#pragma unroll
        for (int q = 0; q < 4; ++q) {
            float4 cv = *(const float4*)(cr + q * 256 + lane * 4);
            float cva[4] = {cv.x, cv.y, cv.z, cv.w};
            unsigned short spa[4];
#pragma unroll
            for (int j = 0; j < 4; ++j) {
                float inp = acc[q][j] + brv[q][j] + cva[j];
                float vv  = v[q][j];
                vv = vv + (inp - vv) * decay;
                bool s = (vv - 1.0f) >= 0.0f;
                v[q][j] = s ? 0.0f : vv;
                spa[j] = s ? (unsigned short)0x3F80 : (unsigned short)0;
                bal[q][j] = __ballot(s);
            }
            ushort4 sp;
            sp.x = spa[0]; sp.y = spa[1]; sp.z = spa[2]; sp.w = spa[3];
            *(ushort4*)(sr + q * 256 + lane * 4) = sp;
        }
        // masks for next step: word w covers cols [64w,64w+64);
        // q = w>>2, 16-lane field = w&3  (round-10-verified formula)
#pragma unroll
        for (int w = 0; w < 16; ++w) {
            int q = w >> 2;
            int f = (w & 3) * 16;
            mask[w] = spread4(bal[q][0] >> f)
                    | (spread4(bal[q][1] >> f) << 1)
                    | (spread4(bal[q][2] >> f) << 2)
                    | (spread4(bal[q][3] >> f) << 3);
        }
    }
}

// ======== MFMA GEMM for fc2 only (feeds BN; loose tolerance) ========
template<int BM, int BN, int WM, int WN, int MI, int NI>
__global__ __launch_bounds__(256)
void mfma_fc2(const unsigned short* __restrict__ Aptr,
              const unsigned short* __restrict__ Bhi,
              const unsigned short* __restrict__ Bmi,
              int K,
              const float* __restrict__ bias,
              float* __restrict__ Cout, int ldc,
              float* __restrict__ partials)
{
    constexpr int LP  = 40;
    constexpr int APL = BM * LP;
    constexpr int BPL = BN * LP;
    __shared__ alignas(16) unsigned short sA[APL];
    __shared__ alignas(16) unsigned short sB[2 * BPL];

    const int nwg = gridDim.x * gridDim.y;
    const int f   = blockIdx.y * gridDim.x + blockIdx.x;
    const int q   = nwg >> 3;
    const int lg  = (f & 7) * q + (f >> 3);
    const int bn0  = (lg % gridDim.x) * BN;
    const int mblk = lg / gridDim.x;
    const int bm0  = mblk * BM;

    const int tid  = threadIdx.x;
    const int lane = tid & 63;
    const int wid  = tid >> 6;
    const int wr   = wid / WN;
    const int wc   = wid % WN;
    const int lr   = lane & 15;
    const int lk   = lane >> 4;

    f32x4 accB[MI][NI], accS[MI][NI];
#pragma unroll
    for (int i = 0; i < MI; ++i)
#pragma unroll
        for (int j = 0; j < NI; ++j) {
            accB[i][j] = (f32x4){0.f, 0.f, 0.f, 0.f};
            accS[i][j] = (f32x4){0.f, 0.f, 0.f, 0.f};
        }

    for (int kt = 0; kt < K; kt += 32) {
#pragma unroll
        for (int p = 0; p < BM / 64; ++p) {
            int e = p * 256 + tid;
            int row = e >> 2, c8 = e & 3;
            int4 v = *(const int4*)(Aptr + (size_t)(bm0 + row) * K + kt + c8 * 8);
            st8x2(&sA[row * LP + c8 * 8], v);
        }
#pragma unroll
        for (int p = 0; p < BN / 64; ++p) {
            int e = p * 256 + tid;
            int row = e >> 2, c8 = e & 3;
            size_t g = (size_t)(bn0 + row) * K + kt + c8 * 8;
            st8x2(&sB[row * LP + c8 * 8],       *(const int4*)(Bhi + g));
            st8x2(&sB[BPL + row * LP + c8 * 8], *(const int4*)(Bmi + g));
        }
        __syncthreads();

        bf16x8 af[MI], b0[NI], b1[NI];
#pragma unroll
        for (int i = 0; i < MI; ++i) {
            int r = wr * MI * 16 + i * 16 + lr;
            af[i] = ld_frag(&sA[r * LP + lk * 8]);
        }
#pragma unroll
        for (int j = 0; j < NI; ++j) {
            int r = wc * NI * 16 + j * 16 + lr;
            b0[j] = ld_frag(&sB[r * LP + lk * 8]);
            b1[j] = ld_frag(&sB[BPL + r * LP + lk * 8]);
        }
#pragma unroll
        for (int i = 0; i < MI; ++i)
#pragma unroll
            for (int j = 0; j < NI; ++j) {
                accB[i][j] = __builtin_amdgcn_mfma_f32_16x16x32_bf16(af[i], b0[j], accB[i][j], 0, 0, 0);
                accS[i][j] = __builtin_amdgcn_mfma_f32_16x16x32_bf16(af[i], b1[j], accS[i][j], 0, 0, 0);
            }
        __syncthreads();
    }

    float csum[NI], csq[NI];
#pragma unroll
    for (int j = 0; j < NI; ++j) { csum[j] = 0.f; csq[j] = 0.f; }
#pragma unroll
    for (int i = 0; i < MI; ++i)
#pragma unroll
        for (int j = 0; j < NI; ++j) {
            int col = bn0 + wc * NI * 16 + j * 16 + lr;
            float bv = bias[col];
#pragma unroll
            for (int r = 0; r < 4; ++r) {
                int row = bm0 + wr * MI * 16 + i * 16 + lk * 4 + r;
                float o = (accB[i][j][r] + accS[i][j][r]) + bv;
                Cout[(size_t)row * ldc + col] = o;
                csum[j] += o;
                csq[j]  += o * o;
            }
        }
    __syncthreads();
    float* redS = (float*)sA;
    float* redQ = (float*)sB;
    const int slot = wr * 4 + lk;
#pragma unroll
    for (int j = 0; j < NI; ++j) {
        int c = wc * NI * 16 + j * 16 + lr;
        redS[slot * BN + c] = csum[j];
        redQ[slot * BN + c] = csq[j];
    }
    __syncthreads();
    if (tid < BN) {
        float s = 0.f, qq = 0.f;
        for (int sl = 0; sl < WM * 4; ++sl) { s += redS[sl * BN + tid]; qq += redQ[sl * BN + tid]; }
        partials[((size_t)mblk * 2 + 0) * O_DIM + bn0 + tid] = s;
        partials[((size_t)mblk * 2 + 1) * O_DIM + bn0 + tid] = qq;
    }
}

__global__ void bn_finalize(const float* __restrict__ partials,
                            const float* __restrict__ gamma,
                            const float* __restrict__ beta,
                            float* __restrict__ scsh, int nmblk)
{
    int o = threadIdx.x;   // 512 threads
    float s = 0.f, q = 0.f;
    for (int mb = 0; mb < nmblk; ++mb) {
        s += partials[((size_t)mb*2 + 0)*O_DIM + o];
        q += partials[((size_t)mb*2 + 1)*O_DIM + o];
    }
    const float invn = 1.f / (float)TBN_DIM;
    float mean = s * invn;
    float var  = q * invn - mean*mean;
    float sc   = gamma[o] * rsqrtf(var + 1e-5f);
    scsh[o]        = sc;
    scsh[O_DIM+o]  = beta[o] - mean*sc;
}

__global__ void bn_apply(float* __restrict__ out, const float* __restrict__ scsh)
{
    const size_t total4 = (size_t)TBN_DIM * O_DIM / 4;
    const float4* sc4 = (const float4*)scsh;
    const float4* sh4 = (const float4*)(scsh + O_DIM);
    size_t stride = (size_t)gridDim.x * blockDim.x;
    for (size_t idx = (size_t)blockIdx.x*blockDim.x + threadIdx.x; idx < total4; idx += stride) {
        float4 v = ((float4*)out)[idx];
        int c4 = (int)(idx & (O_DIM/4 - 1));
        float4 sc = sc4[c4], sh = sh4[c4];
        v.x = v.x*sc.x + sh.x;
        v.y = v.y*sc.y + sh.y;
        v.z = v.z*sc.z + sh.z;
        v.w = v.w*sc.w + sh.w;
        ((float4*)out)[idx] = v;
    }
}

extern "C" void kernel_launch(void* const* d_in, const int* in_sizes, int n_in,
                              void* d_out, int out_size, void* d_ws, size_t ws_size,
                              hipStream_t stream) {
    const float* x     = (const float*)d_in[0];
    const float* W1    = (const float*)d_in[1];
    const float* b1    = (const float*)d_in[2];
    const float* Wrec  = (const float*)d_in[3];
    const float* brec  = (const float*)d_in[4];
    const float* wlif  = (const float*)d_in[5];
    const float* W2    = (const float*)d_in[6];
    const float* b2    = (const float*)d_in[7];
    const float* gamma = (const float*)d_in[8];
    const float* beta  = (const float*)d_in[9];
    float* out = (float*)d_out;

    // ws layout (~407 MB, within round-1's proven 417.3 MB footprint)
    char* w = (char*)d_ws;
    float*          curr  = (float*)w;                            // 256 MB
    unsigned short* spk   = (unsigned short*)(w + 268435456);     // 128 MB
    float*          wrecT = (float*)(w + 402653184);              // 4 MB (scan only)
    unsigned short* w2p   = (unsigned short*)(w + 402653184);     // overlays wrecT after scan
    float* partials = curr;                 // overlay: curr dead after scan
    float* scsh     = curr + 512 * 2 * O_DIM;

    const int W2N = O_DIM * H_DIM;          // 524288

    // fc1: curr = x @ W1^T + b1   (proven frozen-chain fp32 engine)
    gemm_fc1<128,128,16,8,8>
        <<<dim3(H_DIM/128, TBN_DIM/128), 256, 0, stream>>>(
            x, W1, C_DIM, H_DIM, b1, curr);

    // one-time Wrec transpose (needed by the scan)
    wrec_transpose<<<dim3(32, 32), 256, 0, stream>>>(Wrec, wrecT);

    // whole recurrent scan (t=0..31) in ONE kernel, one wave per row
    mega_scan<<<dim3(BNROWS / 4), 256, 0, stream>>>(
        curr, wrecT, brec, wlif, spk);

    // fc2 (BN-only consumer): 2-plane bf16 MFMA + fused BN partials
    split3_w<<<dim3(256), 256, 0, stream>>>(W2, w2p, w2p + W2N, w2p + 2 * W2N, W2N / 4);
    mfma_fc2<128, 128, 2, 2, 4, 4>
        <<<dim3(O_DIM/128, TBN_DIM/128), 256, 0, stream>>>(
            spk, w2p, w2p + W2N, H_DIM, b2, out, O_DIM, partials);

    bn_finalize<<<1, O_DIM, 0, stream>>>(partials, gamma, beta, scsh, TBN_DIM/128);
    bn_apply<<<2048, 256, 0, stream>>>(out, scsh);
}

// Round 14
// 1591.678 us; speedup vs baseline: 2.5652x; 1.2464x over previous
//
#include <hip/hip_runtime.h>
#include <cstdint>
#include <cstddef>

#define T_STEPS 32
#define BNROWS  2048     // B*N
#define C_DIM   512
#define H_DIM   1024
#define O_DIM   512
#define TBN_DIM 65536    // T_STEPS*BNROWS

typedef __attribute__((ext_vector_type(8))) short bf16x8;
typedef __attribute__((ext_vector_type(4))) float f32x4;
typedef __attribute__((ext_vector_type(4))) unsigned short u16x4;

// Exact 3-way truncation split: x == h + m + l exactly.
__device__ __forceinline__ void split3(float x, unsigned short& h,
                                       unsigned short& m, unsigned short& l){
    unsigned u = __float_as_uint(x);
    h = (unsigned short)(u >> 16);
    float r1 = x - __uint_as_float(u & 0xFFFF0000u);
    unsigned u1 = __float_as_uint(r1);
    m = (unsigned short)(u1 >> 16);
    float r2 = r1 - __uint_as_float(u1 & 0xFFFF0000u);
    l = (unsigned short)(__float_as_uint(r2) >> 16);
}

__global__ void split3_w(const float* __restrict__ src,
                         unsigned short* __restrict__ hi,
                         unsigned short* __restrict__ mi,
                         unsigned short* __restrict__ lo, int n4)
{
    int i = blockIdx.x * blockDim.x + threadIdx.x;
    int stride = gridDim.x * blockDim.x;
    for (; i < n4; i += stride) {
        float4 v = ((const float4*)src)[i];
        ushort4 h, m, l;
        split3(v.x, h.x, m.x, l.x); split3(v.y, h.y, m.y, l.y);
        split3(v.z, h.z, m.z, l.z); split3(v.w, h.w, m.w, l.w);
        ((ushort4*)hi)[i] = h;
        ((ushort4*)mi)[i] = m;
        ((ushort4*)lo)[i] = l;
    }
}

// 8-byte-granular LDS helpers for the MFMA kernel (LP=40 ushort rows = 80 B)
__device__ __forceinline__ void st8x2(unsigned short* p, int4 v){
    ((int2*)p)[0] = make_int2(v.x, v.y);
    ((int2*)p)[1] = make_int2(v.z, v.w);
}
__device__ __forceinline__ bf16x8 ld_frag(const unsigned short* p){
    union { bf16x8 v; ushort4 u[2]; } t;
    t.u[0] = *(const ushort4*)(p);
    t.u[1] = *(const ushort4*)(p + 4);
    return t.v;
}

// WrecT[k][n] = Wrec[n][k]  (one-time 4 MB transpose)
__global__ void wrec_transpose(const float* __restrict__ src,
                               float* __restrict__ dst)
{
    __shared__ float tile[32][33];
    const int bx = blockIdx.x * 32, by = blockIdx.y * 32;
    const int tx = threadIdx.x & 31, ty = threadIdx.x >> 5;   // 32x8
#pragma unroll
    for (int r = 0; r < 32; r += 8)
        tile[ty + r][tx] = src[(size_t)(by + ty + r) * H_DIM + bx + tx];
    __syncthreads();
#pragma unroll
    for (int r = 0; r < 32; r += 8)
        dst[(size_t)(bx + ty + r) * H_DIM + by + tx] = tile[tx][ty + r];
}

// ======== fc1: fp32 VALU GEMM, single-buffered (round-7..12 proven chain;
// BK widened 16->32: staging indices only, per-output ascending-k fmaf chain
// and epilogue expressions unchanged -> bit-exact). ========
template<int BM, int BN, int BK, int TM, int TN>
__global__ __launch_bounds__(256)
void gemm_fc1(const float* __restrict__ Ap,
              const float* __restrict__ Bp,
              int K, int ldc,
              const float* __restrict__ bias,
              float* __restrict__ Cout)
{
    constexpr int BMP = BM + 4;
    constexpr int BNP = BN + 4;
    __shared__ float smem[BK*BMP + BK*BNP];
    float* As = smem;
    float* Bs = smem + BK*BMP;

    const int tid = threadIdx.x;
    constexpr int TXN = BN / TN;
    const int tx = tid % TXN;
    const int ty = tid / TXN;
    const int bm0 = blockIdx.y * BM;
    const int bn0 = blockIdx.x * BN;

    constexpr int CPR = BK / 4;

    float acc[TM][TN];
#pragma unroll
    for (int i = 0; i < TM; ++i)
#pragma unroll
        for (int j = 0; j < TN; ++j) acc[i][j] = 0.f;

    for (int kt = 0; kt < K; kt += BK) {
        {
            constexpr int PT = (BM*BK/4)/256;
#pragma unroll
            for (int it = 0; it < PT; ++it) {
                int e   = it*256 + tid;
                int row = e / CPR;
                int c4  = e % CPR;
                float4 fv = *(const float4*)(Ap + (size_t)(bm0+row)*K + kt + c4*4);
                As[(c4*4+0)*BMP + row] = fv.x;
                As[(c4*4+1)*BMP + row] = fv.y;
                As[(c4*4+2)*BMP + row] = fv.z;
                As[(c4*4+3)*BMP + row] = fv.w;
            }
        }
        {
            constexpr int PT = (BN*BK/4)/256;
#pragma unroll
            for (int it = 0; it < PT; ++it) {
                int e   = it*256 + tid;
                int row = e / CPR;
                int c4  = e % CPR;
                float4 fv = *(const float4*)(Bp + (size_t)(bn0+row)*K + kt + c4*4);
                Bs[(c4*4+0)*BNP + row] = fv.x;
                Bs[(c4*4+1)*BNP + row] = fv.y;
                Bs[(c4*4+2)*BNP + row] = fv.z;
                Bs[(c4*4+3)*BNP + row] = fv.w;
            }
        }
        __syncthreads();
#pragma unroll
        for (int k = 0; k < BK; ++k) {
            float a[TM], b[TN];
            float4 t0 = *(const float4*)&As[k*BMP + ty*8];
            float4 t1 = *(const float4*)&As[k*BMP + ty*8 + 4];
            a[0]=t0.x; a[1]=t0.y; a[2]=t0.z; a[3]=t0.w;
            a[4]=t1.x; a[5]=t1.y; a[6]=t1.z; a[7]=t1.w;
            float4 u0 = *(const float4*)&Bs[k*BNP + tx*4];
            float4 u1 = *(const float4*)&Bs[k*BNP + 64 + tx*4];
            b[0]=u0.x; b[1]=u0.y; b[2]=u0.z; b[3]=u0.w;
            b[4]=u1.x; b[5]=u1.y; b[6]=u1.z; b[7]=u1.w;
#pragma unroll
            for (int i = 0; i < TM; ++i)
#pragma unroll
                for (int j = 0; j < TN; ++j)
                    acc[i][j] = fmaf(a[i], b[j], acc[i][j]);
        }
        __syncthreads();
    }

#pragma unroll
    for (int i = 0; i < TM; ++i) {
        int m = bm0 + ty*TM + i;
        int n0 = bn0 + tx*4;
        int n1 = bn0 + 64 + tx*4;
        float4 bv0 = *(const float4*)&bias[n0];
        float4 bv1 = *(const float4*)&bias[n1];
        float4 o0, o1;
        o0.x = acc[i][0] + bv0.x; o0.y = acc[i][1] + bv0.y;
        o0.z = acc[i][2] + bv0.z; o0.w = acc[i][3] + bv0.w;
        o1.x = acc[i][4] + bv1.x; o1.y = acc[i][5] + bv1.y;
        o1.z = acc[i][6] + bv1.z; o1.w = acc[i][7] + bv1.w;
        *(float4*)&Cout[(size_t)m*ldc + n0] = o0;
        *(float4*)&Cout[(size_t)m*ldc + n1] = o1;
    }
}

// Morton spread: 16 bits -> every 4th bit of a 64-bit word (round-10 verified)
__device__ __forceinline__ unsigned long long spread4(unsigned long long x){
    x &= 0xFFFFull;
    x = (x | (x << 24)) & 0x000000FF000000FFull;
    x = (x | (x << 12)) & 0x000F000F000F000Full;
    x = (x | (x << 6 )) & 0x0303030303030303ull;
    x = (x | (x << 3 )) & 0x1111111111111111ull;
    return x;
}

// ======== mega_scan v2: all 32 timesteps, ONE kernel; each row split across
// TWO waves (512 cols each) -> 4096 waves = 16/CU for latency hiding on the
// BW-bound gather. Masks exchanged via ping-pong LDS (1 barrier/step).
// Add sequence identical to round-12's passing chain: words ascending, bits
// ascending, selector-fmaf quads (fmaf(w,1,a)==a+w, fmaf(w,0,a)==a, a never
// -0). PLIF expressions verbatim. curr loads / spk stores are NON-TEMPORAL
// (via clang ext_vector types) so WrecT stays L2-resident and spk skips
// write-allocate.
__global__ __launch_bounds__(256)
void mega_scan(const float* __restrict__ curr,
               const float* __restrict__ WrecT,   // [k][n]
               const float* __restrict__ brec,
               const float* __restrict__ wlif,
               unsigned short* __restrict__ spk)
{
    const int lane = threadIdx.x & 63;
    const int wv   = threadIdx.x >> 6;    // 0..3
    const int r    = wv >> 1;             // row-in-block
    const int h    = wv & 1;              // column half
    const int row  = blockIdx.x * 2 + r;
    const float decay = 1.f / (1.f + expf(-wlif[0]));
    const unsigned long long MSB = 0x8000000000000000ull;

    __shared__ unsigned long long msk[2][2][16];   // [slot][row][word]

    if (threadIdx.x < 32) ((unsigned long long*)msk)[threadIdx.x] = 0ull; // slot 0
    __syncthreads();

    float v[2][4], brv[2][4];
#pragma unroll
    for (int q = 0; q < 2; ++q) {
        float4 bv = *(const float4*)&brec[(2*h + q) * 256 + lane * 4];
        brv[q][0] = bv.x; brv[q][1] = bv.y; brv[q][2] = bv.z; brv[q][3] = bv.w;
#pragma unroll
        for (int j = 0; j < 4; ++j) v[q][j] = 0.f;
    }

    int p = 0;
    for (int t = 0; t < T_STEPS; ++t) {
        float acc[2][4];
#pragma unroll
        for (int q = 0; q < 2; ++q)
#pragma unroll
            for (int j = 0; j < 4; ++j) acc[q][j] = 0.f;

        // ---- sparse gather: words ascending, bits ascending ----
#pragma unroll
        for (int w = 0; w < 16; ++w) {
            unsigned long long mv = msk[p][r][w];
            unsigned lo = __builtin_amdgcn_readfirstlane((unsigned)mv);
            unsigned hi = __builtin_amdgcn_readfirstlane((unsigned)(mv >> 32));
            unsigned long long m = ((unsigned long long)hi << 32) | lo;
            int pc = __popcll(m);
            const float* wbase = WrecT + ((size_t)w << 16) + h * 512 + lane * 4;
            for (int s = 0; s < pc; s += 4) {
                int k0 = __builtin_ctzll(m | MSB); m &= m - 1;
                int k1 = __builtin_ctzll(m | MSB); m &= m - 1;
                int k2 = __builtin_ctzll(m | MSB); m &= m - 1;
                int k3 = __builtin_ctzll(m | MSB); m &= m - 1;
                const float* r0 = wbase + ((size_t)k0 << 10);
                const float* r1 = wbase + ((size_t)k1 << 10);
                const float* r2 = wbase + ((size_t)k2 << 10);
                const float* r3 = wbase + ((size_t)k3 << 10);
                float4 w0[2], w1[2], w2[2], w3[2];
#pragma unroll
                for (int q = 0; q < 2; ++q) {
                    w0[q] = *(const float4*)(r0 + q * 256);
                    w1[q] = *(const float4*)(r1 + q * 256);
                    w2[q] = *(const float4*)(r2 + q * 256);
                    w3[q] = *(const float4*)(r3 + q * 256);
                }
                float s1v = (s + 1 < pc) ? 1.f : 0.f;
                float s2v = (s + 2 < pc) ? 1.f : 0.f;
                float s3v = (s + 3 < pc) ? 1.f : 0.f;
#pragma unroll
                for (int q = 0; q < 2; ++q) {
                    acc[q][0] += w0[q].x;
                    acc[q][0] = fmaf(w1[q].x, s1v, acc[q][0]);
                    acc[q][0] = fmaf(w2[q].x, s2v, acc[q][0]);
                    acc[q][0] = fmaf(w3[q].x, s3v, acc[q][0]);
                    acc[q][1] += w0[q].y;
                    acc[q][1] = fmaf(w1[q].y, s1v, acc[q][1]);
                    acc[q][1] = fmaf(w2[q].y, s2v, acc[q][1]);
                    acc[q][1] = fmaf(w3[q].y, s3v, acc[q][1]);
                    acc[q][2] += w0[q].z;
                    acc[q][2] = fmaf(w1[q].z, s1v, acc[q][2]);
                    acc[q][2] = fmaf(w2[q].z, s2v, acc[q][2]);
                    acc[q][2] = fmaf(w3[q].z, s3v, acc[q][2]);
                    acc[q][3] += w0[q].w;
                    acc[q][3] = fmaf(w1[q].w, s1v, acc[q][3]);
                    acc[q][3] = fmaf(w2[q].w, s2v, acc[q][3]);
                    acc[q][3] = fmaf(w3[q].w, s3v, acc[q][3]);
                }
            }
        }

        // ---- PLIF update + spikes + ballots (verbatim expressions) ----
        const float* cr = curr + (((size_t)t * BNROWS + row) << 10) + h * 512;
        unsigned short* sr = spk + (((size_t)t * BNROWS + row) << 10) + h * 512;
        unsigned long long bal[2][4];
#pragma unroll
        for (int q = 0; q < 2; ++q) {
            f32x4 cv = __builtin_nontemporal_load(
                            (const f32x4*)(cr + q * 256 + lane * 4));
            float cva[4] = {cv[0], cv[1], cv[2], cv[3]};
            unsigned short spa[4];
#pragma unroll
            for (int j = 0; j < 4; ++j) {
                float inp = acc[q][j] + brv[q][j] + cva[j];
                float vv  = v[q][j];
                vv = vv + (inp - vv) * decay;
                bool s = (vv - 1.0f) >= 0.0f;
                v[q][j] = s ? 0.0f : vv;
                spa[j] = s ? (unsigned short)0x3F80 : (unsigned short)0;
                bal[q][j] = __ballot(s);
            }
            u16x4 sp;
            sp[0] = spa[0]; sp[1] = spa[1]; sp[2] = spa[2]; sp[3] = spa[3];
            __builtin_nontemporal_store(sp, (u16x4*)(sr + q * 256 + lane * 4));
        }
        // masks for next step into the other slot (round-10-verified formula)
        if (lane == 0) {
#pragma unroll
            for (int q = 0; q < 2; ++q) {
                int gq = 2 * h + q;
#pragma unroll
                for (int f = 0; f < 4; ++f) {
                    unsigned long long word =
                          spread4(bal[q][0] >> (16 * f))
                        | (spread4(bal[q][1] >> (16 * f)) << 1)
                        | (spread4(bal[q][2] >> (16 * f)) << 2)
                        | (spread4(bal[q][3] >> (16 * f)) << 3);
                    msk[p ^ 1][r][gq * 4 + f] = word;
                }
            }
        }
        __syncthreads();
        p ^= 1;
    }
}

// ======== MFMA GEMM for fc2 only (feeds BN; loose tolerance). 1 bf16 plane
// (hi): weight error 2^-9 rel -> output error ~6e-3 abs vs 0.133 threshold.
template<int BM, int BN, int WM, int WN, int MI, int NI>
__global__ __launch_bounds__(256)
void mfma_fc2(const unsigned short* __restrict__ Aptr,
              const unsigned short* __restrict__ Bhi,
              int K,
              const float* __restrict__ bias,
              float* __restrict__ Cout, int ldc,
              float* __restrict__ partials)
{
    constexpr int LP  = 40;
    constexpr int APL = BM * LP;
    constexpr int BPL = BN * LP;
    __shared__ alignas(16) unsigned short sA[APL];
    __shared__ alignas(16) unsigned short sB[BPL];

    const int nwg = gridDim.x * gridDim.y;
    const int f   = blockIdx.y * gridDim.x + blockIdx.x;
    const int q   = nwg >> 3;
    const int lg  = (f & 7) * q + (f >> 3);
    const int bn0  = (lg % gridDim.x) * BN;
    const int mblk = lg / gridDim.x;
    const int bm0  = mblk * BM;

    const int tid  = threadIdx.x;
    const int lane = tid & 63;
    const int wid  = tid >> 6;
    const int wr   = wid / WN;
    const int wc   = wid % WN;
    const int lr   = lane & 15;
    const int lk   = lane >> 4;

    f32x4 accB[MI][NI];
#pragma unroll
    for (int i = 0; i < MI; ++i)
#pragma unroll
        for (int j = 0; j < NI; ++j)
            accB[i][j] = (f32x4){0.f, 0.f, 0.f, 0.f};

    for (int kt = 0; kt < K; kt += 32) {
#pragma unroll
        for (int p = 0; p < BM / 64; ++p) {
            int e = p * 256 + tid;
            int row = e >> 2, c8 = e & 3;
            int4 v = *(const int4*)(Aptr + (size_t)(bm0 + row) * K + kt + c8 * 8);
            st8x2(&sA[row * LP + c8 * 8], v);
        }
#pragma unroll
        for (int p = 0; p < BN / 64; ++p) {
            int e = p * 256 + tid;
            int row = e >> 2, c8 = e & 3;
            size_t g = (size_t)(bn0 + row) * K + kt + c8 * 8;
            st8x2(&sB[row * LP + c8 * 8], *(const int4*)(Bhi + g));
        }
        __syncthreads();

        bf16x8 af[MI], b0[NI];
#pragma unroll
        for (int i = 0; i < MI; ++i) {
            int r = wr * MI * 16 + i * 16 + lr;
            af[i] = ld_frag(&sA[r * LP + lk * 8]);
        }
#pragma unroll
        for (int j = 0; j < NI; ++j) {
            int r = wc * NI * 16 + j * 16 + lr;
            b0[j] = ld_frag(&sB[r * LP + lk * 8]);
        }
#pragma unroll
        for (int i = 0; i < MI; ++i)
#pragma unroll
            for (int j = 0; j < NI; ++j)
                accB[i][j] = __builtin_amdgcn_mfma_f32_16x16x32_bf16(af[i], b0[j], accB[i][j], 0, 0, 0);
        __syncthreads();
    }

    float csum[NI], csq[NI];
#pragma unroll
    for (int j = 0; j < NI; ++j) { csum[j] = 0.f; csq[j] = 0.f; }
#pragma unroll
    for (int i = 0; i < MI; ++i)
#pragma unroll
        for (int j = 0; j < NI; ++j) {
            int col = bn0 + wc * NI * 16 + j * 16 + lr;
            float bv = bias[col];
#pragma unroll
            for (int r = 0; r < 4; ++r) {
                int row = bm0 + wr * MI * 16 + i * 16 + lk * 4 + r;
                float o = accB[i][j][r] + bv;
                Cout[(size_t)row * ldc + col] = o;
                csum[j] += o;
                csq[j]  += o * o;
            }
        }
    __syncthreads();
    float* redS = (float*)sA;
    float* redQ = (float*)sB;
    const int slot = wr * 4 + lk;
#pragma unroll
    for (int j = 0; j < NI; ++j) {
        int c = wc * NI * 16 + j * 16 + lr;
        redS[slot * BN + c] = csum[j];
        redQ[slot * BN + c] = csq[j];
    }
    __syncthreads();
    if (tid < BN) {
        float s = 0.f, qq = 0.f;
        for (int sl = 0; sl < WM * 4; ++sl) { s += redS[sl * BN + tid]; qq += redQ[sl * BN + tid]; }
        partials[((size_t)mblk * 2 + 0) * O_DIM + bn0 + tid] = s;
        partials[((size_t)mblk * 2 + 1) * O_DIM + bn0 + tid] = qq;
    }
}

__global__ void bn_finalize(const float* __restrict__ partials,
                            const float* __restrict__ gamma,
                            const float* __restrict__ beta,
                            float* __restrict__ scsh, int nmblk)
{
    int o = threadIdx.x;   // 512 threads
    float s = 0.f, q = 0.f;
    for (int mb = 0; mb < nmblk; ++mb) {
        s += partials[((size_t)mb*2 + 0)*O_DIM + o];
        q += partials[((size_t)mb*2 + 1)*O_DIM + o];
    }
    const float invn = 1.f / (float)TBN_DIM;
    float mean = s * invn;
    float var  = q * invn - mean*mean;
    float sc   = gamma[o] * rsqrtf(var + 1e-5f);
    scsh[o]        = sc;
    scsh[O_DIM+o]  = beta[o] - mean*sc;
}

__global__ void bn_apply(float* __restrict__ out, const float* __restrict__ scsh)
{
    const size_t total4 = (size_t)TBN_DIM * O_DIM / 4;
    const float4* sc4 = (const float4*)scsh;
    const float4* sh4 = (const float4*)(scsh + O_DIM);
    size_t stride = (size_t)gridDim.x * blockDim.x;
    for (size_t idx = (size_t)blockIdx.x*blockDim.x + threadIdx.x; idx < total4; idx += stride) {
        float4 v = ((float4*)out)[idx];
        int c4 = (int)(idx & (O_DIM/4 - 1));
        float4 sc = sc4[c4], sh = sh4[c4];
        v.x = v.x*sc.x + sh.x;
        v.y = v.y*sc.y + sh.y;
        v.z = v.z*sc.z + sh.z;
        v.w = v.w*sc.w + sh.w;
        ((float4*)out)[idx] = v;
    }
}

extern "C" void kernel_launch(void* const* d_in, const int* in_sizes, int n_in,
                              void* d_out, int out_size, void* d_ws, size_t ws_size,
                              hipStream_t stream) {
    const float* x     = (const float*)d_in[0];
    const float* W1    = (const float*)d_in[1];
    const float* b1    = (const float*)d_in[2];
    const float* Wrec  = (const float*)d_in[3];
    const float* brec  = (const float*)d_in[4];
    const float* wlif  = (const float*)d_in[5];
    const float* W2    = (const float*)d_in[6];
    const float* b2    = (const float*)d_in[7];
    const float* gamma = (const float*)d_in[8];
    const float* beta  = (const float*)d_in[9];
    float* out = (float*)d_out;

    // ws layout (~407 MB, within round-1's proven 417.3 MB footprint)
    char* w = (char*)d_ws;
    float*          curr  = (float*)w;                            // 256 MB
    unsigned short* spk   = (unsigned short*)(w + 268435456);     // 128 MB
    float*          wrecT = (float*)(w + 402653184);              // 4 MB (scan only)
    unsigned short* w2p   = (unsigned short*)(w + 402653184);     // overlays wrecT after scan
    float* partials = curr;                 // overlay: curr dead after scan
    float* scsh     = curr + 512 * 2 * O_DIM;

    const int W2N = O_DIM * H_DIM;          // 524288

    // fc1: curr = x @ W1^T + b1   (proven frozen-chain fp32 engine, BK=32)
    gemm_fc1<128,128,32,8,8>
        <<<dim3(H_DIM/128, TBN_DIM/128), 256, 0, stream>>>(
            x, W1, C_DIM, H_DIM, b1, curr);

    // one-time Wrec transpose (needed by the scan)
    wrec_transpose<<<dim3(32, 32), 256, 0, stream>>>(Wrec, wrecT);

    // whole recurrent scan (t=0..31) in ONE kernel, 2 waves per row
    mega_scan<<<dim3(BNROWS / 2), 256, 0, stream>>>(
        curr, wrecT, brec, wlif, spk);

    // fc2 (BN-only consumer): 1-plane bf16 MFMA + fused BN partials
    split3_w<<<dim3(256), 256, 0, stream>>>(W2, w2p, w2p + W2N, w2p + 2 * W2N, W2N / 4);
    mfma_fc2<128, 128, 2, 2, 4, 4>
        <<<dim3(O_DIM/128, TBN_DIM/128), 256, 0, stream>>>(
            spk, w2p, H_DIM, b2, out, O_DIM, partials);

    bn_finalize<<<1, O_DIM, 0, stream>>>(partials, gamma, beta, scsh, TBN_DIM/128);
    bn_apply<<<2048, 256, 0, stream>>>(out, scsh);
}

// Round 15
// 1589.572 us; speedup vs baseline: 2.5686x; 1.0013x over previous
//
#include <hip/hip_runtime.h>
#include <cstdint>
#include <cstddef>

#define T_STEPS 32
#define BNROWS  2048     // B*N
#define C_DIM   512
#define H_DIM   1024
#define O_DIM   512
#define TBN_DIM 65536    // T_STEPS*BNROWS

typedef __attribute__((ext_vector_type(8))) short bf16x8;
typedef __attribute__((ext_vector_type(4))) float f32x4;
typedef __attribute__((ext_vector_type(4))) unsigned short u16x4;

// Exact 3-way truncation split: x == h + m + l exactly.
__device__ __forceinline__ void split3(float x, unsigned short& h,
                                       unsigned short& m, unsigned short& l){
    unsigned u = __float_as_uint(x);
    h = (unsigned short)(u >> 16);
    float r1 = x - __uint_as_float(u & 0xFFFF0000u);
    unsigned u1 = __float_as_uint(r1);
    m = (unsigned short)(u1 >> 16);
    float r2 = r1 - __uint_as_float(u1 & 0xFFFF0000u);
    l = (unsigned short)(__float_as_uint(r2) >> 16);
}

__global__ void split3_w(const float* __restrict__ src,
                         unsigned short* __restrict__ hi,
                         unsigned short* __restrict__ mi,
                         unsigned short* __restrict__ lo, int n4)
{
    int i = blockIdx.x * blockDim.x + threadIdx.x;
    int stride = gridDim.x * blockDim.x;
    for (; i < n4; i += stride) {
        float4 v = ((const float4*)src)[i];
        ushort4 h, m, l;
        split3(v.x, h.x, m.x, l.x); split3(v.y, h.y, m.y, l.y);
        split3(v.z, h.z, m.z, l.z); split3(v.w, h.w, m.w, l.w);
        ((ushort4*)hi)[i] = h;
        ((ushort4*)mi)[i] = m;
        ((ushort4*)lo)[i] = l;
    }
}

// 8-byte-granular LDS helpers for the MFMA kernel (LP=40 ushort rows = 80 B)
__device__ __forceinline__ void st8x2(unsigned short* p, int4 v){
    ((int2*)p)[0] = make_int2(v.x, v.y);
    ((int2*)p)[1] = make_int2(v.z, v.w);
}
__device__ __forceinline__ bf16x8 ld_frag(const unsigned short* p){
    union { bf16x8 v; ushort4 u[2]; } t;
    t.u[0] = *(const ushort4*)(p);
    t.u[1] = *(const ushort4*)(p + 4);
    return t.v;
}

// WrecT[k][n] = Wrec[n][k]  (one-time 4 MB transpose)
__global__ void wrec_transpose(const float* __restrict__ src,
                               float* __restrict__ dst)
{
    __shared__ float tile[32][33];
    const int bx = blockIdx.x * 32, by = blockIdx.y * 32;
    const int tx = threadIdx.x & 31, ty = threadIdx.x >> 5;   // 32x8
#pragma unroll
    for (int r = 0; r < 32; r += 8)
        tile[ty + r][tx] = src[(size_t)(by + ty + r) * H_DIM + bx + tx];
    __syncthreads();
#pragma unroll
    for (int r = 0; r < 32; r += 8)
        dst[(size_t)(bx + ty + r) * H_DIM + by + tx] = tile[tx][ty + r];
}

// ======== fc1: fp32 VALU GEMM, single-buffered, BK=16 (rounds 7-12 proven:
// 772-775 us, 72 VGPR, 2-way staging banks). Per-output ascending-k fmaf
// chain and epilogue expressions are the frozen bit-exact spike-path. ========
template<int BM, int BN, int BK, int TM, int TN>
__global__ __launch_bounds__(256)
void gemm_fc1(const float* __restrict__ Ap,
              const float* __restrict__ Bp,
              int K, int ldc,
              const float* __restrict__ bias,
              float* __restrict__ Cout)
{
    constexpr int BMP = BM + 4;
    constexpr int BNP = BN + 4;
    __shared__ float smem[BK*BMP + BK*BNP];
    float* As = smem;
    float* Bs = smem + BK*BMP;

    const int tid = threadIdx.x;
    constexpr int TXN = BN / TN;
    const int tx = tid % TXN;
    const int ty = tid / TXN;
    const int bm0 = blockIdx.y * BM;
    const int bn0 = blockIdx.x * BN;

    constexpr int CPR = BK / 4;

    float acc[TM][TN];
#pragma unroll
    for (int i = 0; i < TM; ++i)
#pragma unroll
        for (int j = 0; j < TN; ++j) acc[i][j] = 0.f;

    for (int kt = 0; kt < K; kt += BK) {
        {
            constexpr int PT = (BM*BK/4)/256;
#pragma unroll
            for (int it = 0; it < PT; ++it) {
                int e   = it*256 + tid;
                int row = e / CPR;
                int c4  = e % CPR;
                float4 fv = *(const float4*)(Ap + (size_t)(bm0+row)*K + kt + c4*4);
                As[(c4*4+0)*BMP + row] = fv.x;
                As[(c4*4+1)*BMP + row] = fv.y;
                As[(c4*4+2)*BMP + row] = fv.z;
                As[(c4*4+3)*BMP + row] = fv.w;
            }
        }
        {
            constexpr int PT = (BN*BK/4)/256;
#pragma unroll
            for (int it = 0; it < PT; ++it) {
                int e   = it*256 + tid;
                int row = e / CPR;
                int c4  = e % CPR;
                float4 fv = *(const float4*)(Bp + (size_t)(bn0+row)*K + kt + c4*4);
                Bs[(c4*4+0)*BNP + row] = fv.x;
                Bs[(c4*4+1)*BNP + row] = fv.y;
                Bs[(c4*4+2)*BNP + row] = fv.z;
                Bs[(c4*4+3)*BNP + row] = fv.w;
            }
        }
        __syncthreads();
#pragma unroll
        for (int k = 0; k < BK; ++k) {
            float a[TM], b[TN];
            float4 t0 = *(const float4*)&As[k*BMP + ty*8];
            float4 t1 = *(const float4*)&As[k*BMP + ty*8 + 4];
            a[0]=t0.x; a[1]=t0.y; a[2]=t0.z; a[3]=t0.w;
            a[4]=t1.x; a[5]=t1.y; a[6]=t1.z; a[7]=t1.w;
            float4 u0 = *(const float4*)&Bs[k*BNP + tx*4];
            float4 u1 = *(const float4*)&Bs[k*BNP + 64 + tx*4];
            b[0]=u0.x; b[1]=u0.y; b[2]=u0.z; b[3]=u0.w;
            b[4]=u1.x; b[5]=u1.y; b[6]=u1.z; b[7]=u1.w;
#pragma unroll
            for (int i = 0; i < TM; ++i)
#pragma unroll
                for (int j = 0; j < TN; ++j)
                    acc[i][j] = fmaf(a[i], b[j], acc[i][j]);
        }
        __syncthreads();
    }

#pragma unroll
    for (int i = 0; i < TM; ++i) {
        int m = bm0 + ty*TM + i;
        int n0 = bn0 + tx*4;
        int n1 = bn0 + 64 + tx*4;
        float4 bv0 = *(const float4*)&bias[n0];
        float4 bv1 = *(const float4*)&bias[n1];
        float4 o0, o1;
        o0.x = acc[i][0] + bv0.x; o0.y = acc[i][1] + bv0.y;
        o0.z = acc[i][2] + bv0.z; o0.w = acc[i][3] + bv0.w;
        o1.x = acc[i][4] + bv1.x; o1.y = acc[i][5] + bv1.y;
        o1.z = acc[i][6] + bv1.z; o1.w = acc[i][7] + bv1.w;
        *(float4*)&Cout[(size_t)m*ldc + n0] = o0;
        *(float4*)&Cout[(size_t)m*ldc + n1] = o1;
    }
}

// Morton spread: 16 bits -> every 4th bit of a 64-bit word (round-10 verified)
__device__ __forceinline__ unsigned long long spread4(unsigned long long x){
    x &= 0xFFFFull;
    x = (x | (x << 24)) & 0x000000FF000000FFull;
    x = (x | (x << 12)) & 0x000F000F000F000Full;
    x = (x | (x << 6 )) & 0x0303030303030303ull;
    x = (x | (x << 3 )) & 0x1111111111111111ull;
    return x;
}

// ======== mega_scan v2 (round-14 proven): all 32 timesteps, ONE kernel;
// each row split across TWO waves (512 cols each) -> 4096 waves = 16/CU.
// Masks exchanged via ping-pong LDS (1 barrier/step). Add sequence identical
// to round-12's passing chain. Non-temporal curr/spk keep WrecT L2-resident.
__global__ __launch_bounds__(256)
void mega_scan(const float* __restrict__ curr,
               const float* __restrict__ WrecT,   // [k][n]
               const float* __restrict__ brec,
               const float* __restrict__ wlif,
               unsigned short* __restrict__ spk)
{
    const int lane = threadIdx.x & 63;
    const int wv   = threadIdx.x >> 6;    // 0..3
    const int r    = wv >> 1;             // row-in-block
    const int h    = wv & 1;              // column half
    const int row  = blockIdx.x * 2 + r;
    const float decay = 1.f / (1.f + expf(-wlif[0]));
    const unsigned long long MSB = 0x8000000000000000ull;

    __shared__ unsigned long long msk[2][2][16];   // [slot][row][word]

    if (threadIdx.x < 32) ((unsigned long long*)msk)[threadIdx.x] = 0ull; // slot 0
    __syncthreads();

    float v[2][4], brv[2][4];
#pragma unroll
    for (int q = 0; q < 2; ++q) {
        float4 bv = *(const float4*)&brec[(2*h + q) * 256 + lane * 4];
        brv[q][0] = bv.x; brv[q][1] = bv.y; brv[q][2] = bv.z; brv[q][3] = bv.w;
#pragma unroll
        for (int j = 0; j < 4; ++j) v[q][j] = 0.f;
    }

    int p = 0;
    for (int t = 0; t < T_STEPS; ++t) {
        float acc[2][4];
#pragma unroll
        for (int q = 0; q < 2; ++q)
#pragma unroll
            for (int j = 0; j < 4; ++j) acc[q][j] = 0.f;

        // ---- sparse gather: words ascending, bits ascending ----
#pragma unroll
        for (int w = 0; w < 16; ++w) {
            unsigned long long mv = msk[p][r][w];
            unsigned lo = __builtin_amdgcn_readfirstlane((unsigned)mv);
            unsigned hi = __builtin_amdgcn_readfirstlane((unsigned)(mv >> 32));
            unsigned long long m = ((unsigned long long)hi << 32) | lo;
            int pc = __popcll(m);
            const float* wbase = WrecT + ((size_t)w << 16) + h * 512 + lane * 4;
            for (int s = 0; s < pc; s += 4) {
                int k0 = __builtin_ctzll(m | MSB); m &= m - 1;
                int k1 = __builtin_ctzll(m | MSB); m &= m - 1;
                int k2 = __builtin_ctzll(m | MSB); m &= m - 1;
                int k3 = __builtin_ctzll(m | MSB); m &= m - 1;
                const float* r0 = wbase + ((size_t)k0 << 10);
                const float* r1 = wbase + ((size_t)k1 << 10);
                const float* r2 = wbase + ((size_t)k2 << 10);
                const float* r3 = wbase + ((size_t)k3 << 10);
                float4 w0[2], w1[2], w2[2], w3[2];
#pragma unroll
                for (int q = 0; q < 2; ++q) {
                    w0[q] = *(const float4*)(r0 + q * 256);
                    w1[q] = *(const float4*)(r1 + q * 256);
                    w2[q] = *(const float4*)(r2 + q * 256);
                    w3[q] = *(const float4*)(r3 + q * 256);
                }
                float s1v = (s + 1 < pc) ? 1.f : 0.f;
                float s2v = (s + 2 < pc) ? 1.f : 0.f;
                float s3v = (s + 3 < pc) ? 1.f : 0.f;
#pragma unroll
                for (int q = 0; q < 2; ++q) {
                    acc[q][0] += w0[q].x;
                    acc[q][0] = fmaf(w1[q].x, s1v, acc[q][0]);
                    acc[q][0] = fmaf(w2[q].x, s2v, acc[q][0]);
                    acc[q][0] = fmaf(w3[q].x, s3v, acc[q][0]);
                    acc[q][1] += w0[q].y;
                    acc[q][1] = fmaf(w1[q].y, s1v, acc[q][1]);
                    acc[q][1] = fmaf(w2[q].y, s2v, acc[q][1]);
                    acc[q][1] = fmaf(w3[q].y, s3v, acc[q][1]);
                    acc[q][2] += w0[q].z;
                    acc[q][2] = fmaf(w1[q].z, s1v, acc[q][2]);
                    acc[q][2] = fmaf(w2[q].z, s2v, acc[q][2]);
                    acc[q][2] = fmaf(w3[q].z, s3v, acc[q][2]);
                    acc[q][3] += w0[q].w;
                    acc[q][3] = fmaf(w1[q].w, s1v, acc[q][3]);
                    acc[q][3] = fmaf(w2[q].w, s2v, acc[q][3]);
                    acc[q][3] = fmaf(w3[q].w, s3v, acc[q][3]);
                }
            }
        }

        // ---- PLIF update + spikes + ballots (verbatim expressions) ----
        const float* cr = curr + (((size_t)t * BNROWS + row) << 10) + h * 512;
        unsigned short* sr = spk + (((size_t)t * BNROWS + row) << 10) + h * 512;
        unsigned long long bal[2][4];
#pragma unroll
        for (int q = 0; q < 2; ++q) {
            f32x4 cv = __builtin_nontemporal_load(
                            (const f32x4*)(cr + q * 256 + lane * 4));
            float cva[4] = {cv[0], cv[1], cv[2], cv[3]};
            unsigned short spa[4];
#pragma unroll
            for (int j = 0; j < 4; ++j) {
                float inp = acc[q][j] + brv[q][j] + cva[j];
                float vv  = v[q][j];
                vv = vv + (inp - vv) * decay;
                bool s = (vv - 1.0f) >= 0.0f;
                v[q][j] = s ? 0.0f : vv;
                spa[j] = s ? (unsigned short)0x3F80 : (unsigned short)0;
                bal[q][j] = __ballot(s);
            }
            u16x4 sp;
            sp[0] = spa[0]; sp[1] = spa[1]; sp[2] = spa[2]; sp[3] = spa[3];
            __builtin_nontemporal_store(sp, (u16x4*)(sr + q * 256 + lane * 4));
        }
        // masks for next step into the other slot (round-10-verified formula)
        if (lane == 0) {
#pragma unroll
            for (int q = 0; q < 2; ++q) {
                int gq = 2 * h + q;
#pragma unroll
                for (int f = 0; f < 4; ++f) {
                    unsigned long long word =
                          spread4(bal[q][0] >> (16 * f))
                        | (spread4(bal[q][1] >> (16 * f)) << 1)
                        | (spread4(bal[q][2] >> (16 * f)) << 2)
                        | (spread4(bal[q][3] >> (16 * f)) << 3);
                    msk[p ^ 1][r][gq * 4 + f] = word;
                }
            }
        }
        __syncthreads();
        p ^= 1;
    }
}

// ======== MFMA GEMM for fc2 only (feeds BN; loose tolerance). 1 bf16 plane
// (hi): weight error 2^-9 rel -> output error ~6e-3 abs vs 0.133 threshold.
template<int BM, int BN, int WM, int WN, int MI, int NI>
__global__ __launch_bounds__(256)
void mfma_fc2(const unsigned short* __restrict__ Aptr,
              const unsigned short* __restrict__ Bhi,
              int K,
              const float* __restrict__ bias,
              float* __restrict__ Cout, int ldc,
              float* __restrict__ partials)
{
    constexpr int LP  = 40;
    constexpr int APL = BM * LP;
    constexpr int BPL = BN * LP;
    __shared__ alignas(16) unsigned short sA[APL];
    __shared__ alignas(16) unsigned short sB[BPL];

    const int nwg = gridDim.x * gridDim.y;
    const int f   = blockIdx.y * gridDim.x + blockIdx.x;
    const int q   = nwg >> 3;
    const int lg  = (f & 7) * q + (f >> 3);
    const int bn0  = (lg % gridDim.x) * BN;
    const int mblk = lg / gridDim.x;
    const int bm0  = mblk * BM;

    const int tid  = threadIdx.x;
    const int lane = tid & 63;
    const int wid  = tid >> 6;
    const int wr   = wid / WN;
    const int wc   = wid % WN;
    const int lr   = lane & 15;
    const int lk   = lane >> 4;

    f32x4 accB[MI][NI];
#pragma unroll
    for (int i = 0; i < MI; ++i)
#pragma unroll
        for (int j = 0; j < NI; ++j)
            accB[i][j] = (f32x4){0.f, 0.f, 0.f, 0.f};

    for (int kt = 0; kt < K; kt += 32) {
#pragma unroll
        for (int p = 0; p < BM / 64; ++p) {
            int e = p * 256 + tid;
            int row = e >> 2, c8 = e & 3;
            int4 v = *(const int4*)(Aptr + (size_t)(bm0 + row) * K + kt + c8 * 8);
            st8x2(&sA[row * LP + c8 * 8], v);
        }
#pragma unroll
        for (int p = 0; p < BN / 64; ++p) {
            int e = p * 256 + tid;
            int row = e >> 2, c8 = e & 3;
            size_t g = (size_t)(bn0 + row) * K + kt + c8 * 8;
            st8x2(&sB[row * LP + c8 * 8], *(const int4*)(Bhi + g));
        }
        __syncthreads();

        bf16x8 af[MI], b0[NI];
#pragma unroll
        for (int i = 0; i < MI; ++i) {
            int r = wr * MI * 16 + i * 16 + lr;
            af[i] = ld_frag(&sA[r * LP + lk * 8]);
        }
#pragma unroll
        for (int j = 0; j < NI; ++j) {
            int r = wc * NI * 16 + j * 16 + lr;
            b0[j] = ld_frag(&sB[r * LP + lk * 8]);
        }
#pragma unroll
        for (int i = 0; i < MI; ++i)
#pragma unroll
            for (int j = 0; j < NI; ++j)
                accB[i][j] = __builtin_amdgcn_mfma_f32_16x16x32_bf16(af[i], b0[j], accB[i][j], 0, 0, 0);
        __syncthreads();
    }

    float csum[NI], csq[NI];
#pragma unroll
    for (int j = 0; j < NI; ++j) { csum[j] = 0.f; csq[j] = 0.f; }
#pragma unroll
    for (int i = 0; i < MI; ++i)
#pragma unroll
        for (int j = 0; j < NI; ++j) {
            int col = bn0 + wc * NI * 16 + j * 16 + lr;
            float bv = bias[col];
#pragma unroll
            for (int r = 0; r < 4; ++r) {
                int row = bm0 + wr * MI * 16 + i * 16 + lk * 4 + r;
                float o = accB[i][j][r] + bv;
                Cout[(size_t)row * ldc + col] = o;
                csum[j] += o;
                csq[j]  += o * o;
            }
        }
    __syncthreads();
    float* redS = (float*)sA;
    float* redQ = (float*)sB;
    const int slot = wr * 4 + lk;
#pragma unroll
    for (int j = 0; j < NI; ++j) {
        int c = wc * NI * 16 + j * 16 + lr;
        redS[slot * BN + c] = csum[j];
        redQ[slot * BN + c] = csq[j];
    }
    __syncthreads();
    if (tid < BN) {
        float s = 0.f, qq = 0.f;
        for (int sl = 0; sl < WM * 4; ++sl) { s += redS[sl * BN + tid]; qq += redQ[sl * BN + tid]; }
        partials[((size_t)mblk * 2 + 0) * O_DIM + bn0 + tid] = s;
        partials[((size_t)mblk * 2 + 1) * O_DIM + bn0 + tid] = qq;
    }
}

__global__ void bn_finalize(const float* __restrict__ partials,
                            const float* __restrict__ gamma,
                            const float* __restrict__ beta,
                            float* __restrict__ scsh, int nmblk)
{
    int o = threadIdx.x;   // 512 threads
    float s = 0.f, q = 0.f;
    for (int mb = 0; mb < nmblk; ++mb) {
        s += partials[((size_t)mb*2 + 0)*O_DIM + o];
        q += partials[((size_t)mb*2 + 1)*O_DIM + o];
    }
    const float invn = 1.f / (float)TBN_DIM;
    float mean = s * invn;
    float var  = q * invn - mean*mean;
    float sc   = gamma[o] * rsqrtf(var + 1e-5f);
    scsh[o]        = sc;
    scsh[O_DIM+o]  = beta[o] - mean*sc;
}

__global__ void bn_apply(float* __restrict__ out, const float* __restrict__ scsh)
{
    const size_t total4 = (size_t)TBN_DIM * O_DIM / 4;
    const float4* sc4 = (const float4*)scsh;
    const float4* sh4 = (const float4*)(scsh + O_DIM);
    size_t stride = (size_t)gridDim.x * blockDim.x;
    for (size_t idx = (size_t)blockIdx.x*blockDim.x + threadIdx.x; idx < total4; idx += stride) {
        float4 v = ((float4*)out)[idx];
        int c4 = (int)(idx & (O_DIM/4 - 1));
        float4 sc = sc4[c4], sh = sh4[c4];
        v.x = v.x*sc.x + sh.x;
        v.y = v.y*sc.y + sh.y;
        v.z = v.z*sc.z + sh.z;
        v.w = v.w*sc.w + sh.w;
        ((float4*)out)[idx] = v;
    }
}

extern "C" void kernel_launch(void* const* d_in, const int* in_sizes, int n_in,
                              void* d_out, int out_size, void* d_ws, size_t ws_size,
                              hipStream_t stream) {
    const float* x     = (const float*)d_in[0];
    const float* W1    = (const float*)d_in[1];
    const float* b1    = (const float*)d_in[2];
    const float* Wrec  = (const float*)d_in[3];
    const float* brec  = (const float*)d_in[4];
    const float* wlif  = (const float*)d_in[5];
    const float* W2    = (const float*)d_in[6];
    const float* b2    = (const float*)d_in[7];
    const float* gamma = (const float*)d_in[8];
    const float* beta  = (const float*)d_in[9];
    float* out = (float*)d_out;

    // ws layout (~407 MB, within round-1's proven 417.3 MB footprint)
    char* w = (char*)d_ws;
    float*          curr  = (float*)w;                            // 256 MB
    unsigned short* spk   = (unsigned short*)(w + 268435456);     // 128 MB
    float*          wrecT = (float*)(w + 402653184);              // 4 MB (scan only)
    unsigned short* w2p   = (unsigned short*)(w + 402653184);     // overlays wrecT after scan
    float* partials = curr;                 // overlay: curr dead after scan
    float* scsh     = curr + 512 * 2 * O_DIM;

    const int W2N = O_DIM * H_DIM;          // 524288

    // fc1: curr = x @ W1^T + b1   (proven frozen-chain fp32 engine, BK=16)
    gemm_fc1<128,128,16,8,8>
        <<<dim3(H_DIM/128, TBN_DIM/128), 256, 0, stream>>>(
            x, W1, C_DIM, H_DIM, b1, curr);

    // one-time Wrec transpose (needed by the scan)
    wrec_transpose<<<dim3(32, 32), 256, 0, stream>>>(Wrec, wrecT);

    // whole recurrent scan (t=0..31) in ONE kernel, 2 waves per row
    mega_scan<<<dim3(BNROWS / 2), 256, 0, stream>>>(
        curr, wrecT, brec, wlif, spk);

    // fc2 (BN-only consumer): 1-plane bf16 MFMA + fused BN partials
    split3_w<<<dim3(256), 256, 0, stream>>>(W2, w2p, w2p + W2N, w2p + 2 * W2N, W2N / 4);
    mfma_fc2<128, 128, 2, 2, 4, 4>
        <<<dim3(O_DIM/128, TBN_DIM/128), 256, 0, stream>>>(
            spk, w2p, H_DIM, b2, out, O_DIM, partials);

    bn_finalize<<<1, O_DIM, 0, stream>>>(partials, gamma, beta, scsh, TBN_DIM/128);
    bn_apply<<<2048, 256, 0, stream>>>(out, scsh);
}